// Round 15
// baseline (140.290 us; speedup 1.0000x reference)
//
#include <hip/hip_runtime.h>

#define L 1024
#define CIN 512
#define NH 32
#define DH 64
#define NB 2
#define AF 2048

typedef unsigned short u16;
typedef unsigned int u32;
typedef __attribute__((ext_vector_type(8))) short bfx8;   // 8 bf16 = 4 VGPR (MFMA A/B frag)
typedef __attribute__((ext_vector_type(4))) short bfx4;   // 8B half-frag
typedef __attribute__((ext_vector_type(4))) float fx4;    // MFMA C/D frag

struct __align__(8) us4 { u16 x, y, z, w; };

#define MFMA16 __builtin_amdgcn_mfma_f32_16x16x32_bf16
#define SBAR() __builtin_amdgcn_s_barrier()
#define SFENCE() __builtin_amdgcn_sched_barrier(0)
#define WAIT_VM(N) asm volatile("s_waitcnt vmcnt(" #N ")" ::: "memory")
#define WAIT_LGKM0() asm volatile("s_waitcnt lgkmcnt(0)" ::: "memory")

__device__ inline void gld16(const void* g, void* l) {
    __builtin_amdgcn_global_load_lds(
        (const __attribute__((address_space(1))) u32*)g,
        (__attribute__((address_space(3))) u32*)l, 16, 0, 0);
}

__device__ inline u16 f2b(float f) {
    union { float f; u32 u; } v; v.f = f;
    u32 u = v.u;
    return (u16)((u + 0x7fffu + ((u >> 16) & 1u)) >> 16);
}

// ---------------------------------------------------------------------------
// prep: all fp32->bf16 weight converts (z=0..4) + x transpose/convert (z=5).
// grid (512, 1, 6), block 256.
// ---------------------------------------------------------------------------
__global__ __launch_bounds__(256) void prep(
    const float* __restrict__ x,
    const float* __restrict__ Wq, const float* __restrict__ Wk, const float* __restrict__ Wv,
    const float* __restrict__ W1, const float* __restrict__ W2,
    u16* __restrict__ xT, u16* __restrict__ Wqb, u16* __restrict__ Wkb,
    u16* __restrict__ Wvb, u16* __restrict__ W1b, u16* __restrict__ W2b)
{
    __shared__ u16 tile[64][68];
    const int z = blockIdx.z;
    const int t = threadIdx.x;
    if (z < 5) {
        const float* in; u16* out; int n4;
        switch (z) {
            case 0: in = Wq; out = Wqb; n4 = AF * CIN / 4; break;
            case 1: in = Wk; out = Wkb; n4 = AF * CIN / 4; break;
            case 2: in = Wv; out = Wvb; n4 = AF * CIN / 4; break;
            case 3: in = W1; out = W1b; n4 = AF * AF / 4; break;
            default: in = W2; out = W2b; n4 = AF * AF / 4; break;
        }
        int i = blockIdx.x * 256 + t;
        for (; i < n4; i += 512 * 256) {
            float4 v = ((const float4*)in)[i];
            us4 o = { f2b(v.x), f2b(v.y), f2b(v.z), f2b(v.w) };
            ((us4*)out)[i] = o;
        }
    } else {
        const int bid = blockIdx.x;
        if (bid >= 256) return;
        const int c0 = (bid & 7) * 64, l0 = ((bid >> 3) & 15) * 64, b = bid >> 7;
        const int tr = t >> 4, tc4 = (t & 15) * 4;
        #pragma unroll
        for (int p = 0; p < 4; ++p) {
            int c = p * 16 + tr;
            float4 v = *(const float4*)(x + ((size_t)(b * CIN + c0 + c)) * L + l0 + tc4);
            tile[c][tc4 + 0] = f2b(v.x); tile[c][tc4 + 1] = f2b(v.y);
            tile[c][tc4 + 2] = f2b(v.z); tile[c][tc4 + 3] = f2b(v.w);
        }
        __syncthreads();
        #pragma unroll
        for (int p = 0; p < 4; ++p) {
            int l = p * 16 + tr;
            us4 o = { tile[tc4 + 0][l], tile[tc4 + 1][l], tile[tc4 + 2][l], tile[tc4 + 3][l] };
            *(us4*)(xT + ((size_t)(b * L + l0 + l)) * CIN + c0 + tc4) = o;
        }
    }
}

// ---------------------------------------------------------------------------
// MFMA GEMM, templated pipeline:
//  BUFS=6: R6 schedule — STAGE before waits, depth-3, 72 KB (2 blocks/CU).
//  BUFS=4: stage-AFTER-barrier depth-3, 48 KB (3 blocks/CU). Proven faster
//          in R14 A/B (W1-final + QKV). Race-free: STAGE(it+3) targets
//          buffer (it-1)%4; all waves passed barrier(it) => compute(it-1)
//          ds_reads retired => safe to overwrite.
// C[M,N] = A[M,K] * B[K,N] (+bias[M], opt relu). A row-major, BT=[N][K].
// Tile 128(M) x 64(N), BK=32, 256 threads = 4 waves (2x2, wave-tile 64x32).
// Grid is ALWAYS (16,16,z): requires M=2048, N=1024. XCD-contiguous remap.
// CT_OUT=1: store C^T bf16 [N][M].  CT_OUT=0: store C fp32 [M][N].
// NA=3 (QKV): grid.z = b*3+which; which==0 scales output by 0.125 (q/sqrt(D));
//             which==2 stores NORMAL orientation bf16 [b][M][N] into Cb2.
// ---------------------------------------------------------------------------
template<int RELU, int CT_OUT, int NA, int BUFS>
__global__ __launch_bounds__(256) void gemm_bt(
    const u16* __restrict__ A0, const u16* __restrict__ A1, const u16* __restrict__ A2,
    const float* __restrict__ bias0, const float* __restrict__ bias1, const float* __restrict__ bias2,
    const u16* __restrict__ BTb, void* __restrict__ Cb, void* __restrict__ Cb2,
    int M, int N, int K, size_t sBT, size_t sC, size_t sWhich)
{
    const int z = blockIdx.z;
    const int which = (NA == 3) ? (z % 3) : 0;
    const int b     = (NA == 3) ? (z / 3) : z;
    const u16* __restrict__ A = (which == 0) ? A0 : (which == 1) ? A1 : A2;
    const float* __restrict__ bias = (which == 0) ? bias0 : (which == 1) ? bias1 : bias2;
    const u16* __restrict__ BT = BTb + (size_t)b * sBT;

    // XCD-contiguous tile remap: XCD k (= lin%8) owns 2 N-columns x all 16 M-tiles
    const int lin  = blockIdx.x + (blockIdx.y << 4);
    const int lin2 = ((lin & 7) << 5) + (lin >> 3);
    const int n0 = (lin2 >> 4) * 64;
    const int m0 = (lin2 & 15) * 128;

    __shared__ u16 lA[BUFS][128 * 32];
    __shared__ u16 lB[BUFS][64 * 32];

    const int t = threadIdx.x, lane = t & 63, wave = t >> 6;
    const int wm = (wave >> 1) * 64, wn = (wave & 1) * 32;
    const int rl = lane & 15, kh = lane >> 4;

    fx4 acc[4][2];
    #pragma unroll
    for (int i = 0; i < 4; ++i)
        #pragma unroll
        for (int j = 0; j < 2; ++j) acc[i][j] = (fx4){0.f, 0.f, 0.f, 0.f};

    // staging: A 512 slots (2/thread), B 256 slots (1/thread); 16B slots
    // slot s -> row s>>2, chunk-pos s&3; src chunk = pos ^ ((row>>1)&3)
    const int sA0 = t, sA1 = t + 256, sB = t;
    const int rA0 = sA0 >> 2, cA0 = (sA0 & 3) ^ ((rA0 >> 1) & 3);
    const int rA1 = sA1 >> 2, cA1 = (sA1 & 3) ^ ((rA1 >> 1) & 3);
    const int rB  = sB  >> 2, cB  = (sB  & 3) ^ ((rB  >> 1) & 3);
    const u16* gA0 = A  + (size_t)(m0 + rA0) * K + cA0 * 8;
    const u16* gA1 = A  + (size_t)(m0 + rA1) * K + cA1 * 8;
    const u16* gB0 = BT + (size_t)(n0 + rB) * K + cB * 8;

    // frag read offsets: row r, k-chunk kh -> r*32 + ((kh ^ ((r>>1)&3))*8)
    int aoff[4], boff[2];
    #pragma unroll
    for (int f = 0; f < 4; ++f) {
        int ra = wm + f * 16 + rl;
        aoff[f] = ra * 32 + ((kh ^ ((ra >> 1) & 3)) * 8);
    }
    #pragma unroll
    for (int f = 0; f < 2; ++f) {
        int rb = wn + f * 16 + rl;
        boff[f] = rb * 32 + ((kh ^ ((rb >> 1) & 3)) * 8);
    }

#define STAGE(BF, K0) do { \
        gld16(gA0 + (K0), &lA[BF][sA0 * 8]); \
        gld16(gA1 + (K0), &lA[BF][sA1 * 8]); \
        gld16(gB0 + (K0), &lB[BF][sB  * 8]); } while (0)

#define COMPUTE(BF) do { \
        const u16* bA_ = lA[BF]; \
        const u16* bB_ = lB[BF]; \
        bfx8 af[4], bfr[2]; \
        af[0] = *(const bfx8*)&bA_[aoff[0]]; \
        af[1] = *(const bfx8*)&bA_[aoff[1]]; \
        af[2] = *(const bfx8*)&bA_[aoff[2]]; \
        af[3] = *(const bfx8*)&bA_[aoff[3]]; \
        bfr[0] = *(const bfx8*)&bB_[boff[0]]; \
        bfr[1] = *(const bfx8*)&bB_[boff[1]]; \
        __builtin_amdgcn_s_setprio(1); \
        _Pragma("unroll") \
        for (int fm = 0; fm < 4; ++fm) \
            _Pragma("unroll") \
            for (int fn = 0; fn < 2; ++fn) \
                acc[fm][fn] = MFMA16(af[fm], bfr[fn], acc[fm][fn], 0, 0, 0); \
        __builtin_amdgcn_s_setprio(0); } while (0)

    const int NT = K >> 5;   // 16 (QKV) or 64 (finals)
    if (BUFS == 6) {
        // --- R6 schedule: STAGE before waits, 6 buffers ---
        STAGE(0, 0); STAGE(1, 32); STAGE(2, 64);
        WAIT_VM(6); SBAR(); SFENCE();
        int bcur = 0, bpre = 3;
        for (int it = 0; it < NT; ++it) {
            if (it + 3 < NT) {
                STAGE(bpre, (it + 3) << 5);
                WAIT_VM(9);
            } else if (it + 2 < NT) {
                WAIT_VM(6);
            } else if (it + 1 < NT) {
                WAIT_VM(3);
            } else {
                WAIT_VM(0);
            }
            SBAR(); SFENCE();
            COMPUTE(bcur);
            if (++bcur == BUFS) bcur = 0;
            if (++bpre == BUFS) bpre = 0;
        }
    } else {
        // --- BUFS=4: stage-after-barrier, 48 KB ---
        STAGE(0, 0); STAGE(1, 32); STAGE(2, 64);
        for (int it = 0; it < NT; ++it) {
            const int rem = NT - 1 - it;
            if (rem >= 2) { WAIT_VM(6); }
            else if (rem == 1) { WAIT_VM(3); }
            else { WAIT_VM(0); }
            SBAR(); SFENCE();
            if (it + 3 < NT) STAGE((it + 3) & 3, (it + 3) << 5);
            COMPUTE(it & 3);
        }
    }
#undef STAGE
#undef COMPUTE

    if (NA == 3 && which == 2) {
        // v: store normal orientation bf16 [b][M][N]
        u16* Vn = (u16*)Cb2 + (size_t)b * (size_t)M * N;
        #pragma unroll
        for (int fm = 0; fm < 4; ++fm) {
            int mg = m0 + wm + fm * 16 + kh * 4;
            #pragma unroll
            for (int fn = 0; fn < 2; ++fn) {
                int ng = n0 + wn + fn * 16 + rl;
                #pragma unroll
                for (int r = 0; r < 4; ++r)
                    Vn[(size_t)(mg + r) * N + ng] = f2b(acc[fm][fn][r] + bias[mg + r]);
            }
        }
    } else if (CT_OUT) {
        const float sc = (NA == 3 && which == 0) ? 0.125f : 1.0f;
        u16* CT = (u16*)Cb + (size_t)which * sWhich + (size_t)b * sC;
        #pragma unroll
        for (int fm = 0; fm < 4; ++fm) {
            int mg = m0 + wm + fm * 16 + kh * 4;
            float bi0 = bias[mg], bi1 = bias[mg + 1], bi2 = bias[mg + 2], bi3 = bias[mg + 3];
            #pragma unroll
            for (int fn = 0; fn < 2; ++fn) {
                int ng = n0 + wn + fn * 16 + rl;
                float v0 = (acc[fm][fn][0] + bi0) * sc;
                float v1 = (acc[fm][fn][1] + bi1) * sc;
                float v2 = (acc[fm][fn][2] + bi2) * sc;
                float v3 = (acc[fm][fn][3] + bi3) * sc;
                if (RELU) {
                    v0 = fmaxf(v0, 0.f); v1 = fmaxf(v1, 0.f);
                    v2 = fmaxf(v2, 0.f); v3 = fmaxf(v3, 0.f);
                }
                us4 o = { f2b(v0), f2b(v1), f2b(v2), f2b(v3) };
                *(us4*)(CT + (size_t)ng * M + mg) = o;
            }
        }
    } else {
        float* C = (float*)Cb + (size_t)b * sC;
        #pragma unroll
        for (int fm = 0; fm < 4; ++fm) {
            int mg = m0 + wm + fm * 16 + kh * 4;
            #pragma unroll
            for (int fn = 0; fn < 2; ++fn) {
                int ng = n0 + wn + fn * 16 + rl;
                #pragma unroll
                for (int r = 0; r < 4; ++r) {
                    float v = acc[fm][fn][r] + bias[mg + r];
                    if (RELU) v = fmaxf(v, 0.f);
                    C[(size_t)(mg + r) * N + ng] = v;
                }
            }
        }
    }
}

// ---------------------------------------------------------------------------
// Pass A (BANDED +-1 tile, W=64): S[l] = sum_{m in tiles [lt-1,lt+1]}
// exp(att[l,m] - |l-m|/8). Verified numerically free in R12/R13.
// Block = 64 l-rows of one (b,h). grid (16, B*H). Depth-2 prefetch.
// ---------------------------------------------------------------------------
__global__ __launch_bounds__(256) void attn_stats(
    const u16* __restrict__ qT, const u16* __restrict__ kT,
    float* __restrict__ rinv)
{
    const int lt = blockIdx.x;
    const int bh = blockIdx.y;
    const int b = bh >> 5, h = bh & 31;
    const size_t base = (size_t)b * L * AF + h * DH;

    const int mlo = lt < 1 ? 0 : lt - 1;
    const int mhi = lt > 14 ? 15 : lt + 1;
    const int NTW = mhi - mlo + 1;   // 2..3 always

    __shared__ u16 lq[64 * 64];
    __shared__ u16 lk[4][64 * 64];
    __shared__ float sS[4][64];

    const int t = threadIdx.x, lane = t & 63, wave = t >> 6;
    const int rl = lane & 15, g = lane >> 4;

    const int s0 = t, s1 = t + 256;
    const int r0 = s0 >> 3, cs0 = (s0 & 7) ^ (r0 & 7);
    const int r1 = s1 >> 3, cs1 = (s1 & 7) ^ (r1 & 7);

    const u16* gk0 = kT + base + (size_t)(mlo * 64 + r0) * AF + cs0 * 8;
    const u16* gk1 = kT + base + (size_t)(mlo * 64 + r1) * AF + cs1 * 8;

    gld16(qT + base + (size_t)(lt * 64 + r0) * AF + cs0 * 8, lq + s0 * 8);
    gld16(qT + base + (size_t)(lt * 64 + r1) * AF + cs1 * 8, lq + s1 * 8);
    gld16(gk0, &lk[0][s0 * 8]);
    gld16(gk1, &lk[0][s1 * 8]);
    gld16(gk0 + (size_t)64 * AF, &lk[1][s0 * 8]);
    gld16(gk1 + (size_t)64 * AF, &lk[1][s1 * 8]);
    WAIT_VM(2); SBAR(); SFENCE();    // q + k0 landed

    const int rmr = wave * 16 + rl;
    const int akoff0 = rmr * 64 + ((g ^ (rmr & 7)) * 8);
    const int akoff1 = rmr * 64 + (((g + 4) ^ (rmr & 7)) * 8);
    bfx8 qf0[4], qf1[4];
    #pragma unroll
    for (int f = 0; f < 4; ++f) {
        int rq = f * 16 + rl;
        qf0[f] = *(const bfx8*)&lq[rq * 64 + ((g ^ (rq & 7)) * 8)];
        qf1[f] = *(const bfx8*)&lq[rq * 64 + (((g + 4) ^ (rq & 7)) * 8)];
    }

    float Sx[4] = {0.f, 0.f, 0.f, 0.f};
    for (int i = 0; i < NTW; ++i) {
        if (i + 2 < NTW) {
            const int bf = (i + 2) & 3;
            gld16(gk0 + (size_t)(i + 2) * 64 * AF, &lk[bf][s0 * 8]);
            gld16(gk1 + (size_t)(i + 2) * 64 * AF, &lk[bf][s1 * 8]);
            WAIT_VM(4);
        } else if (i + 1 < NTW) {
            WAIT_VM(2);
        } else {
            WAIT_VM(0);
        }
        SBAR(); SFENCE();
        const u16* kb = lk[i & 3];
        bfx8 ak0 = *(const bfx8*)&kb[akoff0];
        bfx8 ak1 = *(const bfx8*)&kb[akoff1];
        const float mb = (float)((mlo + i) * 64 + wave * 16 + g * 4);
        #pragma unroll
        for (int fn = 0; fn < 4; ++fn) {
            fx4 att = (fx4){0.f, 0.f, 0.f, 0.f};
            att = MFMA16(ak0, qf0[fn], att, 0, 0, 0);
            att = MFMA16(ak1, qf1[fn], att, 0, 0, 0);
            const float lgf = (float)(lt * 64 + fn * 16 + rl);
            float e0 = __expf(att[0] - 0.125f * fabsf(lgf - mb));
            float e1 = __expf(att[1] - 0.125f * fabsf(lgf - (mb + 1.f)));
            float e2 = __expf(att[2] - 0.125f * fabsf(lgf - (mb + 2.f)));
            float e3 = __expf(att[3] - 0.125f * fabsf(lgf - (mb + 3.f)));
            Sx[fn] += (e0 + e1) + (e2 + e3);
        }
    }
    #pragma unroll
    for (int fn = 0; fn < 4; ++fn) {
        float s_ = Sx[fn];
        s_ += __shfl_xor(s_, 16);
        s_ += __shfl_xor(s_, 32);
        if (lane < 16) sS[wave][fn * 16 + rl] = s_;
    }
    __syncthreads();
    if (t < 64) {
        float s_ = sS[0][t] + sS[1][t] + sS[2][t] + sS[3][t];
        rinv[(size_t)bh * L + lt * 64 + t] = 1.0f / s_;
    }
}

// ---------------------------------------------------------------------------
// Pass B (BANDED +-1 tile): O[d,m] = sum over l-tiles [mt-1, mt] of
// v[d,l]*w[l,m]; h = relu(O) -> hT[b][m][h*64+d]. grid (16, B*H).
// ---------------------------------------------------------------------------
__global__ __launch_bounds__(256) void attn_pv(
    const u16* __restrict__ qT, const u16* __restrict__ kT, const u16* __restrict__ v,
    const float* __restrict__ rinv, u16* __restrict__ hT)
{
    const int mt = blockIdx.x;
    const int bh = blockIdx.y;
    const int b = bh >> 5, h = bh & 31;
    const size_t qkbase = (size_t)b * L * AF + h * DH;
    const size_t vbase  = ((size_t)b * AF + h * DH) * L;
    const size_t rbase  = (size_t)bh * L;

    const int ltlo = mt < 1 ? 0 : mt - 1;
    const int NI = mt - ltlo + 1;    // 1..2
    const int m0 = mt * 64;

    __shared__ u16 lkt[64 * 64];
    __shared__ u16 lqt[2][64 * 64], lv[2][64 * 64];
    __shared__ u16 lw[64 * 68];   // wT[m][l], pad 68

    const int t = threadIdx.x, lane = t & 63, wave = t >> 6;
    const int rl = lane & 15, g = lane >> 4;

    const int s0 = t, s1 = t + 256;
    const int r0 = s0 >> 3, cs0 = (s0 & 7) ^ (r0 & 7);
    const int r1 = s1 >> 3, cs1 = (s1 & 7) ^ (r1 & 7);

    const u16* gq0 = qT + qkbase + (size_t)(ltlo * 64 + r0) * AF + cs0 * 8;
    const u16* gq1 = qT + qkbase + (size_t)(ltlo * 64 + r1) * AF + cs1 * 8;
    const u16* gv0 = v + vbase + ltlo * 64 + (size_t)r0 * L + cs0 * 8;
    const u16* gv1 = v + vbase + ltlo * 64 + (size_t)r1 * L + cs1 * 8;

    const int rmr = wave * 16 + rl;     // phase-1 A rows (m), phase-2 A rows (d)
    const int toff0 = rmr * 64 + ((g ^ (rmr & 7)) * 8);
    const int toff1 = rmr * 64 + (((g + 4) ^ (rmr & 7)) * 8);
    int qoff0[4], qoff1[4];
    #pragma unroll
    for (int f = 0; f < 4; ++f) {
        int rq = f * 16 + rl;
        qoff0[f] = rq * 64 + ((g ^ (rq & 7)) * 8);
        qoff1[f] = rq * 64 + (((g + 4) ^ (rq & 7)) * 8);
    }

    // prologue: K-tile + first q/v tile
    gld16(kT + qkbase + (size_t)(m0 + r0) * AF + cs0 * 8, lkt + s0 * 8);
    gld16(kT + qkbase + (size_t)(m0 + r1) * AF + cs1 * 8, lkt + s1 * 8);
    gld16(gq0, &lqt[0][s0 * 8]);
    gld16(gq1, &lqt[0][s1 * 8]);
    gld16(gv0, &lv[0][s0 * 8]);
    gld16(gv1, &lv[0][s1 * 8]);
    WAIT_VM(0); SBAR(); SFENCE();

    fx4 oa[4];
    #pragma unroll
    for (int f = 0; f < 4; ++f) oa[f] = (fx4){0.f, 0.f, 0.f, 0.f};

    int cur = 0;
    for (int i = 0; i < NI; ++i) {
        const int lt = ltlo + i;
        if (i + 1 < NI) {   // prefetch next q/v tile into the other buffer
            gld16(gq0 + (size_t)(i + 1) * 64 * AF, &lqt[cur ^ 1][s0 * 8]);
            gld16(gq1 + (size_t)(i + 1) * 64 * AF, &lqt[cur ^ 1][s1 * 8]);
            gld16(gv0 + (i + 1) * 64, &lv[cur ^ 1][s0 * 8]);
            gld16(gv1 + (i + 1) * 64, &lv[cur ^ 1][s1 * 8]);
        }
        // phase 1: att^T[m][l] = mfma(kT rows m, qT rows l) -> weights in lw
        bfx8 ak0 = *(const bfx8*)&lkt[toff0];
        bfx8 ak1 = *(const bfx8*)&lkt[toff1];
        const u16* qb = lqt[cur];
        #pragma unroll
        for (int fn = 0; fn < 4; ++fn) {
            bfx8 q0 = *(const bfx8*)&qb[qoff0[fn]];
            bfx8 q1 = *(const bfx8*)&qb[qoff1[fn]];
            fx4 att = (fx4){0.f, 0.f, 0.f, 0.f};
            att = MFMA16(ak0, q0, att, 0, 0, 0);
            att = MFMA16(ak1, q1, att, 0, 0, 0);
            const int lg = lt * 64 + fn * 16 + rl;
            float ri = rinv[rbase + lg];
            const float db = (float)(lg - (m0 + wave * 16 + g * 4));
            #pragma unroll
            for (int r = 0; r < 4; ++r) {
                int mloc = wave * 16 + g * 4 + r;
                float s = att[r] - 0.125f * fabsf(db - (float)r);
                float w = (lg <= m0 + mloc) ? __expf(s) * ri : 0.f;
                lw[mloc * 68 + fn * 16 + rl] = f2b(w);
            }
        }
        WAIT_LGKM0(); SBAR(); SFENCE();   // lw visible; prefetch stays in flight

        // phase 2: O[d][m] += mfma(v rows d, wT rows m)
        const u16* vb = lv[cur];
        bfx8 av0 = *(const bfx8*)&vb[toff0];
        bfx8 av1 = *(const bfx8*)&vb[toff1];
        #pragma unroll
        for (int fn = 0; fn < 4; ++fn) {
            const u16* wrow = &lw[(fn * 16 + rl) * 68];
            union { bfx8 f; bfx4 hh[2]; } w0, w1;
            w0.hh[0] = *(const bfx4*)&wrow[g * 8];
            w0.hh[1] = *(const bfx4*)&wrow[g * 8 + 4];
            w1.hh[0] = *(const bfx4*)&wrow[(g + 4) * 8];
            w1.hh[1] = *(const bfx4*)&wrow[(g + 4) * 8 + 4];
            oa[fn] = MFMA16(av0, w0.f, oa[fn], 0, 0, 0);
            oa[fn] = MFMA16(av1, w1.f, oa[fn], 0, 0, 0);
        }
        WAIT_VM(0); WAIT_LGKM0(); SBAR(); SFENCE();   // next tile landed; reads done
        cur ^= 1;
    }

    // epilogue: relu, C^T store -> hT[b][m][h*64+d]
    #pragma unroll
    for (int fn = 0; fn < 4; ++fn) {
        int mg = m0 + fn * 16 + rl;
        int cg = h * DH + wave * 16 + g * 4;
        us4 o = { f2b(fmaxf(oa[fn][0], 0.f)), f2b(fmaxf(oa[fn][1], 0.f)),
                  f2b(fmaxf(oa[fn][2], 0.f)), f2b(fmaxf(oa[fn][3], 0.f)) };
        *(us4*)(hT + ((size_t)b * L + mg) * AF + cg) = o;
    }
}

// ---------------------------------------------------------------------------
extern "C" void kernel_launch(void* const* d_in, const int* in_sizes, int n_in,
                              void* d_out, int out_size, void* d_ws, size_t ws_size,
                              hipStream_t stream)
{
    (void)in_sizes; (void)n_in; (void)out_size; (void)ws_size;
    const float* x  = (const float*)d_in[0];
    const float* Wq = (const float*)d_in[1];
    const float* bq = (const float*)d_in[2];
    const float* Wk = (const float*)d_in[3];
    const float* bk = (const float*)d_in[4];
    const float* Wv = (const float*)d_in[5];
    const float* bv = (const float*)d_in[6];
    const float* W1 = (const float*)d_in[7];
    const float* b1 = (const float*)d_in[8];
    const float* W2 = (const float*)d_in[9];
    const float* b2 = (const float*)d_in[10];

    u16* wsp = (u16*)d_ws;
    size_t o = 0;
    u16* xT  = wsp + o; o += (size_t)NB * L * CIN;
    u16* qT  = wsp + o; o += (size_t)NB * L * AF;   // q (pre-scaled by 1/8), [b][l][af]
    u16* kT  = wsp + o; o += (size_t)NB * L * AF;   // must follow qT (which*sWhich)
    u16* vdm = wsp + o; o += (size_t)NB * AF * L;   // v normal orientation [b][af][l]
    u16* hT  = wsp + o; o += (size_t)NB * L * AF;
    u16* z1T = wsp + o; o += (size_t)NB * L * AF;
    u16* Wqb = wsp + o; o += (size_t)AF * CIN;
    u16* Wkb = wsp + o; o += (size_t)AF * CIN;
    u16* Wvb = wsp + o; o += (size_t)AF * CIN;
    u16* W1b = wsp + o; o += (size_t)AF * AF;
    u16* W2b = wsp + o; o += (size_t)AF * AF;
    float* rinv = (float*)(wsp + o); o += (size_t)NB * NH * L * 2;

    dim3 blk(256);

    prep<<<dim3(512, 1, 6), blk, 0, stream>>>(x, Wq, Wk, Wv, W1, W2,
                                              xT, Wqb, Wkb, Wvb, W1b, W2b);

    // QKV: qT/kT = (W? * x)^T (q scaled 1/8); v -> vdm normal orientation
    gemm_bt<0, 1, 3, 4><<<dim3(16, 16, NB * 3), blk, 0, stream>>>(
        Wqb, Wkb, Wvb, bq, bk, bv, xT, qT, vdm,
        AF, L, CIN, (size_t)L * CIN, (size_t)L * AF, (size_t)NB * L * AF);

    attn_stats<<<dim3(16, NB * NH), blk, 0, stream>>>(qT, kT, rinv);
    attn_pv<<<dim3(16, NB * NH), blk, 0, stream>>>(qT, kT, vdm, rinv, hT);

    // z1T = relu(W1*h + b1)^T  -- BUFS=4 (won R14 A/B)
    gemm_bt<1, 1, 1, 4><<<dim3(16, 16, NB), blk, 0, stream>>>(
        W1b, nullptr, nullptr, b1, nullptr, nullptr, hT, z1T, nullptr,
        AF, L, AF, (size_t)L * AF, (size_t)L * AF, 0);
    // out = W2*z1 + b2 (fp32) -- BUFS=4 rollout (was 6)
    gemm_bt<0, 0, 1, 4><<<dim3(16, 16, NB), blk, 0, stream>>>(
        W2b, nullptr, nullptr, b2, nullptr, nullptr, z1T, d_out, nullptr,
        AF, L, AF, (size_t)L * AF, (size_t)AF * L, 0);
}

// Round 16
// 138.546 us; speedup vs baseline: 1.0126x; 1.0126x over previous
//
#include <hip/hip_runtime.h>

#define L 1024
#define CIN 512
#define NH 32
#define DH 64
#define NB 2
#define AF 2048

typedef unsigned short u16;
typedef unsigned int u32;
typedef __attribute__((ext_vector_type(8))) short bfx8;   // 8 bf16 = 4 VGPR (MFMA A/B frag)
typedef __attribute__((ext_vector_type(4))) short bfx4;   // 8B half-frag
typedef __attribute__((ext_vector_type(4))) float fx4;    // MFMA C/D frag

struct __align__(8) us4 { u16 x, y, z, w; };

#define MFMA16 __builtin_amdgcn_mfma_f32_16x16x32_bf16
#define SBAR() __builtin_amdgcn_s_barrier()
#define SFENCE() __builtin_amdgcn_sched_barrier(0)
#define WAIT_VM(N) asm volatile("s_waitcnt vmcnt(" #N ")" ::: "memory")
#define WAIT_LGKM0() asm volatile("s_waitcnt lgkmcnt(0)" ::: "memory")

__device__ inline void gld16(const void* g, void* l) {
    __builtin_amdgcn_global_load_lds(
        (const __attribute__((address_space(1))) u32*)g,
        (__attribute__((address_space(3))) u32*)l, 16, 0, 0);
}

__device__ inline u16 f2b(float f) {
    union { float f; u32 u; } v; v.f = f;
    u32 u = v.u;
    return (u16)((u + 0x7fffu + ((u >> 16) & 1u)) >> 16);
}

// ---------------------------------------------------------------------------
// prep: all fp32->bf16 weight converts (z=0..4) + x transpose/convert (z=5).
// grid (512, 1, 6), block 256.
// ---------------------------------------------------------------------------
__global__ __launch_bounds__(256) void prep(
    const float* __restrict__ x,
    const float* __restrict__ Wq, const float* __restrict__ Wk, const float* __restrict__ Wv,
    const float* __restrict__ W1, const float* __restrict__ W2,
    u16* __restrict__ xT, u16* __restrict__ Wqb, u16* __restrict__ Wkb,
    u16* __restrict__ Wvb, u16* __restrict__ W1b, u16* __restrict__ W2b)
{
    __shared__ u16 tile[64][68];
    const int z = blockIdx.z;
    const int t = threadIdx.x;
    if (z < 5) {
        const float* in; u16* out; int n4;
        switch (z) {
            case 0: in = Wq; out = Wqb; n4 = AF * CIN / 4; break;
            case 1: in = Wk; out = Wkb; n4 = AF * CIN / 4; break;
            case 2: in = Wv; out = Wvb; n4 = AF * CIN / 4; break;
            case 3: in = W1; out = W1b; n4 = AF * AF / 4; break;
            default: in = W2; out = W2b; n4 = AF * AF / 4; break;
        }
        int i = blockIdx.x * 256 + t;
        for (; i < n4; i += 512 * 256) {
            float4 v = ((const float4*)in)[i];
            us4 o = { f2b(v.x), f2b(v.y), f2b(v.z), f2b(v.w) };
            ((us4*)out)[i] = o;
        }
    } else {
        const int bid = blockIdx.x;
        if (bid >= 256) return;
        const int c0 = (bid & 7) * 64, l0 = ((bid >> 3) & 15) * 64, b = bid >> 7;
        const int tr = t >> 4, tc4 = (t & 15) * 4;
        #pragma unroll
        for (int p = 0; p < 4; ++p) {
            int c = p * 16 + tr;
            float4 v = *(const float4*)(x + ((size_t)(b * CIN + c0 + c)) * L + l0 + tc4);
            tile[c][tc4 + 0] = f2b(v.x); tile[c][tc4 + 1] = f2b(v.y);
            tile[c][tc4 + 2] = f2b(v.z); tile[c][tc4 + 3] = f2b(v.w);
        }
        __syncthreads();
        #pragma unroll
        for (int p = 0; p < 4; ++p) {
            int l = p * 16 + tr;
            us4 o = { tile[tc4 + 0][l], tile[tc4 + 1][l], tile[tc4 + 2][l], tile[tc4 + 3][l] };
            *(us4*)(xT + ((size_t)(b * L + l0 + l)) * CIN + c0 + tc4) = o;
        }
    }
}

// ---------------------------------------------------------------------------
// MFMA GEMM, templated pipeline:
//  BUFS=6: R6 schedule — STAGE before waits, depth-3, 72 KB (2 blocks/CU).
//          Best for fp32 strided epilogue (W2 final; R15 A/B).
//  BUFS=4: stage-AFTER-barrier depth-3, 48 KB (3 blocks/CU). Best for bf16
//          C^T epilogues (QKV, W1 final; R14 A/B). Race-free: STAGE(it+3)
//          targets buffer (it-1)%4; all waves passed barrier(it) =>
//          compute(it-1) ds_reads retired => safe to overwrite.
// C[M,N] = A[M,K] * B[K,N] (+bias[M], opt relu). A row-major, BT=[N][K].
// Tile 128(M) x 64(N), BK=32, 256 threads = 4 waves (2x2, wave-tile 64x32).
// Grid is ALWAYS (16,16,z): requires M=2048, N=1024. XCD-contiguous remap.
// CT_OUT=1: store C^T bf16 [N][M].  CT_OUT=0: store C fp32 [M][N].
// NA=3 (QKV): grid.z = b*3+which; which==0 scales output by 0.125 (q/sqrt(D));
//             which==2 stores NORMAL orientation bf16 [b][M][N] into Cb2.
// ---------------------------------------------------------------------------
template<int RELU, int CT_OUT, int NA, int BUFS>
__global__ __launch_bounds__(256) void gemm_bt(
    const u16* __restrict__ A0, const u16* __restrict__ A1, const u16* __restrict__ A2,
    const float* __restrict__ bias0, const float* __restrict__ bias1, const float* __restrict__ bias2,
    const u16* __restrict__ BTb, void* __restrict__ Cb, void* __restrict__ Cb2,
    int M, int N, int K, size_t sBT, size_t sC, size_t sWhich)
{
    const int z = blockIdx.z;
    const int which = (NA == 3) ? (z % 3) : 0;
    const int b     = (NA == 3) ? (z / 3) : z;
    const u16* __restrict__ A = (which == 0) ? A0 : (which == 1) ? A1 : A2;
    const float* __restrict__ bias = (which == 0) ? bias0 : (which == 1) ? bias1 : bias2;
    const u16* __restrict__ BT = BTb + (size_t)b * sBT;

    // XCD-contiguous tile remap: XCD k (= lin%8) owns 2 N-columns x all 16 M-tiles
    const int lin  = blockIdx.x + (blockIdx.y << 4);
    const int lin2 = ((lin & 7) << 5) + (lin >> 3);
    const int n0 = (lin2 >> 4) * 64;
    const int m0 = (lin2 & 15) * 128;

    __shared__ u16 lA[BUFS][128 * 32];
    __shared__ u16 lB[BUFS][64 * 32];

    const int t = threadIdx.x, lane = t & 63, wave = t >> 6;
    const int wm = (wave >> 1) * 64, wn = (wave & 1) * 32;
    const int rl = lane & 15, kh = lane >> 4;

    fx4 acc[4][2];
    #pragma unroll
    for (int i = 0; i < 4; ++i)
        #pragma unroll
        for (int j = 0; j < 2; ++j) acc[i][j] = (fx4){0.f, 0.f, 0.f, 0.f};

    // staging: A 512 slots (2/thread), B 256 slots (1/thread); 16B slots
    // slot s -> row s>>2, chunk-pos s&3; src chunk = pos ^ ((row>>1)&3)
    const int sA0 = t, sA1 = t + 256, sB = t;
    const int rA0 = sA0 >> 2, cA0 = (sA0 & 3) ^ ((rA0 >> 1) & 3);
    const int rA1 = sA1 >> 2, cA1 = (sA1 & 3) ^ ((rA1 >> 1) & 3);
    const int rB  = sB  >> 2, cB  = (sB  & 3) ^ ((rB  >> 1) & 3);
    const u16* gA0 = A  + (size_t)(m0 + rA0) * K + cA0 * 8;
    const u16* gA1 = A  + (size_t)(m0 + rA1) * K + cA1 * 8;
    const u16* gB0 = BT + (size_t)(n0 + rB) * K + cB * 8;

    // frag read offsets: row r, k-chunk kh -> r*32 + ((kh ^ ((r>>1)&3))*8)
    int aoff[4], boff[2];
    #pragma unroll
    for (int f = 0; f < 4; ++f) {
        int ra = wm + f * 16 + rl;
        aoff[f] = ra * 32 + ((kh ^ ((ra >> 1) & 3)) * 8);
    }
    #pragma unroll
    for (int f = 0; f < 2; ++f) {
        int rb = wn + f * 16 + rl;
        boff[f] = rb * 32 + ((kh ^ ((rb >> 1) & 3)) * 8);
    }

#define STAGE(BF, K0) do { \
        gld16(gA0 + (K0), &lA[BF][sA0 * 8]); \
        gld16(gA1 + (K0), &lA[BF][sA1 * 8]); \
        gld16(gB0 + (K0), &lB[BF][sB  * 8]); } while (0)

#define COMPUTE(BF) do { \
        const u16* bA_ = lA[BF]; \
        const u16* bB_ = lB[BF]; \
        bfx8 af[4], bfr[2]; \
        af[0] = *(const bfx8*)&bA_[aoff[0]]; \
        af[1] = *(const bfx8*)&bA_[aoff[1]]; \
        af[2] = *(const bfx8*)&bA_[aoff[2]]; \
        af[3] = *(const bfx8*)&bA_[aoff[3]]; \
        bfr[0] = *(const bfx8*)&bB_[boff[0]]; \
        bfr[1] = *(const bfx8*)&bB_[boff[1]]; \
        __builtin_amdgcn_s_setprio(1); \
        _Pragma("unroll") \
        for (int fm = 0; fm < 4; ++fm) \
            _Pragma("unroll") \
            for (int fn = 0; fn < 2; ++fn) \
                acc[fm][fn] = MFMA16(af[fm], bfr[fn], acc[fm][fn], 0, 0, 0); \
        __builtin_amdgcn_s_setprio(0); } while (0)

    const int NT = K >> 5;   // 16 (QKV) or 64 (finals)
    if (BUFS == 6) {
        // --- R6 schedule: STAGE before waits, 6 buffers ---
        STAGE(0, 0); STAGE(1, 32); STAGE(2, 64);
        WAIT_VM(6); SBAR(); SFENCE();
        int bcur = 0, bpre = 3;
        for (int it = 0; it < NT; ++it) {
            if (it + 3 < NT) {
                STAGE(bpre, (it + 3) << 5);
                WAIT_VM(9);
            } else if (it + 2 < NT) {
                WAIT_VM(6);
            } else if (it + 1 < NT) {
                WAIT_VM(3);
            } else {
                WAIT_VM(0);
            }
            SBAR(); SFENCE();
            COMPUTE(bcur);
            if (++bcur == BUFS) bcur = 0;
            if (++bpre == BUFS) bpre = 0;
        }
    } else {
        // --- BUFS=4: stage-after-barrier, 48 KB ---
        STAGE(0, 0); STAGE(1, 32); STAGE(2, 64);
        for (int it = 0; it < NT; ++it) {
            const int rem = NT - 1 - it;
            if (rem >= 2) { WAIT_VM(6); }
            else if (rem == 1) { WAIT_VM(3); }
            else { WAIT_VM(0); }
            SBAR(); SFENCE();
            if (it + 3 < NT) STAGE((it + 3) & 3, (it + 3) << 5);
            COMPUTE(it & 3);
        }
    }
#undef STAGE
#undef COMPUTE

    if (NA == 3 && which == 2) {
        // v: store normal orientation bf16 [b][M][N]
        u16* Vn = (u16*)Cb2 + (size_t)b * (size_t)M * N;
        #pragma unroll
        for (int fm = 0; fm < 4; ++fm) {
            int mg = m0 + wm + fm * 16 + kh * 4;
            #pragma unroll
            for (int fn = 0; fn < 2; ++fn) {
                int ng = n0 + wn + fn * 16 + rl;
                #pragma unroll
                for (int r = 0; r < 4; ++r)
                    Vn[(size_t)(mg + r) * N + ng] = f2b(acc[fm][fn][r] + bias[mg + r]);
            }
        }
    } else if (CT_OUT) {
        const float sc = (NA == 3 && which == 0) ? 0.125f : 1.0f;
        u16* CT = (u16*)Cb + (size_t)which * sWhich + (size_t)b * sC;
        #pragma unroll
        for (int fm = 0; fm < 4; ++fm) {
            int mg = m0 + wm + fm * 16 + kh * 4;
            float bi0 = bias[mg], bi1 = bias[mg + 1], bi2 = bias[mg + 2], bi3 = bias[mg + 3];
            #pragma unroll
            for (int fn = 0; fn < 2; ++fn) {
                int ng = n0 + wn + fn * 16 + rl;
                float v0 = (acc[fm][fn][0] + bi0) * sc;
                float v1 = (acc[fm][fn][1] + bi1) * sc;
                float v2 = (acc[fm][fn][2] + bi2) * sc;
                float v3 = (acc[fm][fn][3] + bi3) * sc;
                if (RELU) {
                    v0 = fmaxf(v0, 0.f); v1 = fmaxf(v1, 0.f);
                    v2 = fmaxf(v2, 0.f); v3 = fmaxf(v3, 0.f);
                }
                us4 o = { f2b(v0), f2b(v1), f2b(v2), f2b(v3) };
                *(us4*)(CT + (size_t)ng * M + mg) = o;
            }
        }
    } else {
        float* C = (float*)Cb + (size_t)b * sC;
        #pragma unroll
        for (int fm = 0; fm < 4; ++fm) {
            int mg = m0 + wm + fm * 16 + kh * 4;
            #pragma unroll
            for (int fn = 0; fn < 2; ++fn) {
                int ng = n0 + wn + fn * 16 + rl;
                #pragma unroll
                for (int r = 0; r < 4; ++r) {
                    float v = acc[fm][fn][r] + bias[mg + r];
                    if (RELU) v = fmaxf(v, 0.f);
                    C[(size_t)(mg + r) * N + ng] = v;
                }
            }
        }
    }
}

// ---------------------------------------------------------------------------
// Pass A (BANDED +-1 tile, W=64): S[l] = sum_{m in tiles [lt-1,lt+1]}
// exp(att[l,m] - |l-m|/8). Verified numerically free in R12/R13.
// Block = 64 l-rows of one (b,h). grid (16, B*H). Depth-2 prefetch.
// ---------------------------------------------------------------------------
__global__ __launch_bounds__(256) void attn_stats(
    const u16* __restrict__ qT, const u16* __restrict__ kT,
    float* __restrict__ rinv)
{
    const int lt = blockIdx.x;
    const int bh = blockIdx.y;
    const int b = bh >> 5, h = bh & 31;
    const size_t base = (size_t)b * L * AF + h * DH;

    const int mlo = lt < 1 ? 0 : lt - 1;
    const int mhi = lt > 14 ? 15 : lt + 1;
    const int NTW = mhi - mlo + 1;   // 2..3 always

    __shared__ u16 lq[64 * 64];
    __shared__ u16 lk[4][64 * 64];
    __shared__ float sS[4][64];

    const int t = threadIdx.x, lane = t & 63, wave = t >> 6;
    const int rl = lane & 15, g = lane >> 4;

    const int s0 = t, s1 = t + 256;
    const int r0 = s0 >> 3, cs0 = (s0 & 7) ^ (r0 & 7);
    const int r1 = s1 >> 3, cs1 = (s1 & 7) ^ (r1 & 7);

    const u16* gk0 = kT + base + (size_t)(mlo * 64 + r0) * AF + cs0 * 8;
    const u16* gk1 = kT + base + (size_t)(mlo * 64 + r1) * AF + cs1 * 8;

    gld16(qT + base + (size_t)(lt * 64 + r0) * AF + cs0 * 8, lq + s0 * 8);
    gld16(qT + base + (size_t)(lt * 64 + r1) * AF + cs1 * 8, lq + s1 * 8);
    gld16(gk0, &lk[0][s0 * 8]);
    gld16(gk1, &lk[0][s1 * 8]);
    gld16(gk0 + (size_t)64 * AF, &lk[1][s0 * 8]);
    gld16(gk1 + (size_t)64 * AF, &lk[1][s1 * 8]);
    WAIT_VM(2); SBAR(); SFENCE();    // q + k0 landed

    const int rmr = wave * 16 + rl;
    const int akoff0 = rmr * 64 + ((g ^ (rmr & 7)) * 8);
    const int akoff1 = rmr * 64 + (((g + 4) ^ (rmr & 7)) * 8);
    bfx8 qf0[4], qf1[4];
    #pragma unroll
    for (int f = 0; f < 4; ++f) {
        int rq = f * 16 + rl;
        qf0[f] = *(const bfx8*)&lq[rq * 64 + ((g ^ (rq & 7)) * 8)];
        qf1[f] = *(const bfx8*)&lq[rq * 64 + (((g + 4) ^ (rq & 7)) * 8)];
    }

    float Sx[4] = {0.f, 0.f, 0.f, 0.f};
    for (int i = 0; i < NTW; ++i) {
        if (i + 2 < NTW) {
            const int bf = (i + 2) & 3;
            gld16(gk0 + (size_t)(i + 2) * 64 * AF, &lk[bf][s0 * 8]);
            gld16(gk1 + (size_t)(i + 2) * 64 * AF, &lk[bf][s1 * 8]);
            WAIT_VM(4);
        } else if (i + 1 < NTW) {
            WAIT_VM(2);
        } else {
            WAIT_VM(0);
        }
        SBAR(); SFENCE();
        const u16* kb = lk[i & 3];
        bfx8 ak0 = *(const bfx8*)&kb[akoff0];
        bfx8 ak1 = *(const bfx8*)&kb[akoff1];
        const float mb = (float)((mlo + i) * 64 + wave * 16 + g * 4);
        #pragma unroll
        for (int fn = 0; fn < 4; ++fn) {
            fx4 att = (fx4){0.f, 0.f, 0.f, 0.f};
            att = MFMA16(ak0, qf0[fn], att, 0, 0, 0);
            att = MFMA16(ak1, qf1[fn], att, 0, 0, 0);
            const float lgf = (float)(lt * 64 + fn * 16 + rl);
            float e0 = __expf(att[0] - 0.125f * fabsf(lgf - mb));
            float e1 = __expf(att[1] - 0.125f * fabsf(lgf - (mb + 1.f)));
            float e2 = __expf(att[2] - 0.125f * fabsf(lgf - (mb + 2.f)));
            float e3 = __expf(att[3] - 0.125f * fabsf(lgf - (mb + 3.f)));
            Sx[fn] += (e0 + e1) + (e2 + e3);
        }
    }
    #pragma unroll
    for (int fn = 0; fn < 4; ++fn) {
        float s_ = Sx[fn];
        s_ += __shfl_xor(s_, 16);
        s_ += __shfl_xor(s_, 32);
        if (lane < 16) sS[wave][fn * 16 + rl] = s_;
    }
    __syncthreads();
    if (t < 64) {
        float s_ = sS[0][t] + sS[1][t] + sS[2][t] + sS[3][t];
        rinv[(size_t)bh * L + lt * 64 + t] = 1.0f / s_;
    }
}

// ---------------------------------------------------------------------------
// Pass B (BANDED +-1 tile): O[d,m] = sum over l-tiles [mt-1, mt] of
// v[d,l]*w[l,m]; h = relu(O) -> hT[b][m][h*64+d]. grid (16, B*H).
// ---------------------------------------------------------------------------
__global__ __launch_bounds__(256) void attn_pv(
    const u16* __restrict__ qT, const u16* __restrict__ kT, const u16* __restrict__ v,
    const float* __restrict__ rinv, u16* __restrict__ hT)
{
    const int mt = blockIdx.x;
    const int bh = blockIdx.y;
    const int b = bh >> 5, h = bh & 31;
    const size_t qkbase = (size_t)b * L * AF + h * DH;
    const size_t vbase  = ((size_t)b * AF + h * DH) * L;
    const size_t rbase  = (size_t)bh * L;

    const int ltlo = mt < 1 ? 0 : mt - 1;
    const int NI = mt - ltlo + 1;    // 1..2
    const int m0 = mt * 64;

    __shared__ u16 lkt[64 * 64];
    __shared__ u16 lqt[2][64 * 64], lv[2][64 * 64];
    __shared__ u16 lw[64 * 68];   // wT[m][l], pad 68

    const int t = threadIdx.x, lane = t & 63, wave = t >> 6;
    const int rl = lane & 15, g = lane >> 4;

    const int s0 = t, s1 = t + 256;
    const int r0 = s0 >> 3, cs0 = (s0 & 7) ^ (r0 & 7);
    const int r1 = s1 >> 3, cs1 = (s1 & 7) ^ (r1 & 7);

    const u16* gq0 = qT + qkbase + (size_t)(ltlo * 64 + r0) * AF + cs0 * 8;
    const u16* gq1 = qT + qkbase + (size_t)(ltlo * 64 + r1) * AF + cs1 * 8;
    const u16* gv0 = v + vbase + ltlo * 64 + (size_t)r0 * L + cs0 * 8;
    const u16* gv1 = v + vbase + ltlo * 64 + (size_t)r1 * L + cs1 * 8;

    const int rmr = wave * 16 + rl;     // phase-1 A rows (m), phase-2 A rows (d)
    const int toff0 = rmr * 64 + ((g ^ (rmr & 7)) * 8);
    const int toff1 = rmr * 64 + (((g + 4) ^ (rmr & 7)) * 8);
    int qoff0[4], qoff1[4];
    #pragma unroll
    for (int f = 0; f < 4; ++f) {
        int rq = f * 16 + rl;
        qoff0[f] = rq * 64 + ((g ^ (rq & 7)) * 8);
        qoff1[f] = rq * 64 + (((g + 4) ^ (rq & 7)) * 8);
    }

    // prologue: K-tile + first q/v tile
    gld16(kT + qkbase + (size_t)(m0 + r0) * AF + cs0 * 8, lkt + s0 * 8);
    gld16(kT + qkbase + (size_t)(m0 + r1) * AF + cs1 * 8, lkt + s1 * 8);
    gld16(gq0, &lqt[0][s0 * 8]);
    gld16(gq1, &lqt[0][s1 * 8]);
    gld16(gv0, &lv[0][s0 * 8]);
    gld16(gv1, &lv[0][s1 * 8]);
    WAIT_VM(0); SBAR(); SFENCE();

    fx4 oa[4];
    #pragma unroll
    for (int f = 0; f < 4; ++f) oa[f] = (fx4){0.f, 0.f, 0.f, 0.f};

    int cur = 0;
    for (int i = 0; i < NI; ++i) {
        const int lt = ltlo + i;
        if (i + 1 < NI) {   // prefetch next q/v tile into the other buffer
            gld16(gq0 + (size_t)(i + 1) * 64 * AF, &lqt[cur ^ 1][s0 * 8]);
            gld16(gq1 + (size_t)(i + 1) * 64 * AF, &lqt[cur ^ 1][s1 * 8]);
            gld16(gv0 + (i + 1) * 64, &lv[cur ^ 1][s0 * 8]);
            gld16(gv1 + (i + 1) * 64, &lv[cur ^ 1][s1 * 8]);
        }
        // phase 1: att^T[m][l] = mfma(kT rows m, qT rows l) -> weights in lw
        bfx8 ak0 = *(const bfx8*)&lkt[toff0];
        bfx8 ak1 = *(const bfx8*)&lkt[toff1];
        const u16* qb = lqt[cur];
        #pragma unroll
        for (int fn = 0; fn < 4; ++fn) {
            bfx8 q0 = *(const bfx8*)&qb[qoff0[fn]];
            bfx8 q1 = *(const bfx8*)&qb[qoff1[fn]];
            fx4 att = (fx4){0.f, 0.f, 0.f, 0.f};
            att = MFMA16(ak0, q0, att, 0, 0, 0);
            att = MFMA16(ak1, q1, att, 0, 0, 0);
            const int lg = lt * 64 + fn * 16 + rl;
            float ri = rinv[rbase + lg];
            const float db = (float)(lg - (m0 + wave * 16 + g * 4));
            #pragma unroll
            for (int r = 0; r < 4; ++r) {
                int mloc = wave * 16 + g * 4 + r;
                float s = att[r] - 0.125f * fabsf(db - (float)r);
                float w = (lg <= m0 + mloc) ? __expf(s) * ri : 0.f;
                lw[mloc * 68 + fn * 16 + rl] = f2b(w);
            }
        }
        WAIT_LGKM0(); SBAR(); SFENCE();   // lw visible; prefetch stays in flight

        // phase 2: O[d][m] += mfma(v rows d, wT rows m)
        const u16* vb = lv[cur];
        bfx8 av0 = *(const bfx8*)&vb[toff0];
        bfx8 av1 = *(const bfx8*)&vb[toff1];
        #pragma unroll
        for (int fn = 0; fn < 4; ++fn) {
            const u16* wrow = &lw[(fn * 16 + rl) * 68];
            union { bfx8 f; bfx4 hh[2]; } w0, w1;
            w0.hh[0] = *(const bfx4*)&wrow[g * 8];
            w0.hh[1] = *(const bfx4*)&wrow[g * 8 + 4];
            w1.hh[0] = *(const bfx4*)&wrow[(g + 4) * 8];
            w1.hh[1] = *(const bfx4*)&wrow[(g + 4) * 8 + 4];
            oa[fn] = MFMA16(av0, w0.f, oa[fn], 0, 0, 0);
            oa[fn] = MFMA16(av1, w1.f, oa[fn], 0, 0, 0);
        }
        WAIT_VM(0); WAIT_LGKM0(); SBAR(); SFENCE();   // next tile landed; reads done
        cur ^= 1;
    }

    // epilogue: relu, C^T store -> hT[b][m][h*64+d]
    #pragma unroll
    for (int fn = 0; fn < 4; ++fn) {
        int mg = m0 + fn * 16 + rl;
        int cg = h * DH + wave * 16 + g * 4;
        us4 o = { f2b(fmaxf(oa[fn][0], 0.f)), f2b(fmaxf(oa[fn][1], 0.f)),
                  f2b(fmaxf(oa[fn][2], 0.f)), f2b(fmaxf(oa[fn][3], 0.f)) };
        *(us4*)(hT + ((size_t)b * L + mg) * AF + cg) = o;
    }
}

// ---------------------------------------------------------------------------
extern "C" void kernel_launch(void* const* d_in, const int* in_sizes, int n_in,
                              void* d_out, int out_size, void* d_ws, size_t ws_size,
                              hipStream_t stream)
{
    (void)in_sizes; (void)n_in; (void)out_size; (void)ws_size;
    const float* x  = (const float*)d_in[0];
    const float* Wq = (const float*)d_in[1];
    const float* bq = (const float*)d_in[2];
    const float* Wk = (const float*)d_in[3];
    const float* bk = (const float*)d_in[4];
    const float* Wv = (const float*)d_in[5];
    const float* bv = (const float*)d_in[6];
    const float* W1 = (const float*)d_in[7];
    const float* b1 = (const float*)d_in[8];
    const float* W2 = (const float*)d_in[9];
    const float* b2 = (const float*)d_in[10];

    u16* wsp = (u16*)d_ws;
    size_t o = 0;
    u16* xT  = wsp + o; o += (size_t)NB * L * CIN;
    u16* qT  = wsp + o; o += (size_t)NB * L * AF;   // q (pre-scaled by 1/8), [b][l][af]
    u16* kT  = wsp + o; o += (size_t)NB * L * AF;   // must follow qT (which*sWhich)
    u16* vdm = wsp + o; o += (size_t)NB * AF * L;   // v normal orientation [b][af][l]
    u16* hT  = wsp + o; o += (size_t)NB * L * AF;
    u16* z1T = wsp + o; o += (size_t)NB * L * AF;
    u16* Wqb = wsp + o; o += (size_t)AF * CIN;
    u16* Wkb = wsp + o; o += (size_t)AF * CIN;
    u16* Wvb = wsp + o; o += (size_t)AF * CIN;
    u16* W1b = wsp + o; o += (size_t)AF * AF;
    u16* W2b = wsp + o; o += (size_t)AF * AF;
    float* rinv = (float*)(wsp + o); o += (size_t)NB * NH * L * 2;

    dim3 blk(256);

    prep<<<dim3(512, 1, 6), blk, 0, stream>>>(x, Wq, Wk, Wv, W1, W2,
                                              xT, Wqb, Wkb, Wvb, W1b, W2b);

    // QKV: qT/kT = (W? * x)^T (q scaled 1/8); v -> vdm normal orientation
    gemm_bt<0, 1, 3, 4><<<dim3(16, 16, NB * 3), blk, 0, stream>>>(
        Wqb, Wkb, Wvb, bq, bk, bv, xT, qT, vdm,
        AF, L, CIN, (size_t)L * CIN, (size_t)L * AF, (size_t)NB * L * AF);

    attn_stats<<<dim3(16, NB * NH), blk, 0, stream>>>(qT, kT, rinv);
    attn_pv<<<dim3(16, NB * NH), blk, 0, stream>>>(qT, kT, vdm, rinv, hT);

    // z1T = relu(W1*h + b1)^T  -- BUFS=4 (bf16 C^T epilogue; won R14 A/B)
    gemm_bt<1, 1, 1, 4><<<dim3(16, 16, NB), blk, 0, stream>>>(
        W1b, nullptr, nullptr, b1, nullptr, nullptr, hT, z1T, nullptr,
        AF, L, AF, (size_t)L * AF, (size_t)L * AF, 0);
    // out = W2*z1 + b2 (fp32 strided epilogue) -- BUFS=6 (won R15 A/B)
    gemm_bt<0, 0, 1, 6><<<dim3(16, 16, NB), blk, 0, stream>>>(
        W2b, nullptr, nullptr, b2, nullptr, nullptr, z1T, d_out, nullptr,
        AF, L, AF, (size_t)L * AF, (size_t)AF * L, 0);
}

// Round 17
// 134.178 us; speedup vs baseline: 1.0456x; 1.0326x over previous
//
#include <hip/hip_runtime.h>

#define L 1024
#define CIN 512
#define NH 32
#define DH 64
#define NB 2
#define AF 2048

typedef unsigned short u16;
typedef unsigned int u32;
typedef __attribute__((ext_vector_type(8))) short bfx8;   // 8 bf16 = 4 VGPR (MFMA A/B frag)
typedef __attribute__((ext_vector_type(4))) short bfx4;   // 8B half-frag
typedef __attribute__((ext_vector_type(4))) float fx4;    // MFMA C/D frag

struct __align__(8) us4 { u16 x, y, z, w; };

#define MFMA16 __builtin_amdgcn_mfma_f32_16x16x32_bf16
#define SBAR() __builtin_amdgcn_s_barrier()
#define SFENCE() __builtin_amdgcn_sched_barrier(0)
#define WAIT_VM(N) asm volatile("s_waitcnt vmcnt(" #N ")" ::: "memory")
#define WAIT_LGKM0() asm volatile("s_waitcnt lgkmcnt(0)" ::: "memory")

__device__ inline void gld16(const void* g, void* l) {
    __builtin_amdgcn_global_load_lds(
        (const __attribute__((address_space(1))) u32*)g,
        (__attribute__((address_space(3))) u32*)l, 16, 0, 0);
}

__device__ inline u16 f2b(float f) {
    union { float f; u32 u; } v; v.f = f;
    u32 u = v.u;
    return (u16)((u + 0x7fffu + ((u >> 16) & 1u)) >> 16);
}

// ---------------------------------------------------------------------------
// prep: all fp32->bf16 weight converts (z=0..4) + x transpose/convert (z=5).
// grid (512, 1, 6), block 256.
// ---------------------------------------------------------------------------
__global__ __launch_bounds__(256) void prep(
    const float* __restrict__ x,
    const float* __restrict__ Wq, const float* __restrict__ Wk, const float* __restrict__ Wv,
    const float* __restrict__ W1, const float* __restrict__ W2,
    u16* __restrict__ xT, u16* __restrict__ Wqb, u16* __restrict__ Wkb,
    u16* __restrict__ Wvb, u16* __restrict__ W1b, u16* __restrict__ W2b)
{
    __shared__ u16 tile[64][68];
    const int z = blockIdx.z;
    const int t = threadIdx.x;
    if (z < 5) {
        const float* in; u16* out; int n4;
        switch (z) {
            case 0: in = Wq; out = Wqb; n4 = AF * CIN / 4; break;
            case 1: in = Wk; out = Wkb; n4 = AF * CIN / 4; break;
            case 2: in = Wv; out = Wvb; n4 = AF * CIN / 4; break;
            case 3: in = W1; out = W1b; n4 = AF * AF / 4; break;
            default: in = W2; out = W2b; n4 = AF * AF / 4; break;
        }
        int i = blockIdx.x * 256 + t;
        for (; i < n4; i += 512 * 256) {
            float4 v = ((const float4*)in)[i];
            us4 o = { f2b(v.x), f2b(v.y), f2b(v.z), f2b(v.w) };
            ((us4*)out)[i] = o;
        }
    } else {
        const int bid = blockIdx.x;
        if (bid >= 256) return;
        const int c0 = (bid & 7) * 64, l0 = ((bid >> 3) & 15) * 64, b = bid >> 7;
        const int tr = t >> 4, tc4 = (t & 15) * 4;
        #pragma unroll
        for (int p = 0; p < 4; ++p) {
            int c = p * 16 + tr;
            float4 v = *(const float4*)(x + ((size_t)(b * CIN + c0 + c)) * L + l0 + tc4);
            tile[c][tc4 + 0] = f2b(v.x); tile[c][tc4 + 1] = f2b(v.y);
            tile[c][tc4 + 2] = f2b(v.z); tile[c][tc4 + 3] = f2b(v.w);
        }
        __syncthreads();
        #pragma unroll
        for (int p = 0; p < 4; ++p) {
            int l = p * 16 + tr;
            us4 o = { tile[tc4 + 0][l], tile[tc4 + 1][l], tile[tc4 + 2][l], tile[tc4 + 3][l] };
            *(us4*)(xT + ((size_t)(b * L + l0 + l)) * CIN + c0 + tc4) = o;
        }
    }
}

// ---------------------------------------------------------------------------
// MFMA GEMM, templated pipeline (BUFS selects schedule):
//  BUFS=6: BK=32, STAGE-before-waits depth-3, 72 KB (2 blocks/CU). Best for
//          fp32 strided epilogue (W2; R15 A/B).
//  BUFS=4: BK=32, stage-after-barrier depth-3, 48 KB (3 blocks/CU). Best for
//          bf16 C^T epilogues at BK32 (R14 A/B).
//  BUFS=3: BK=64, stage-after-barrier depth-2, 72 KB (2 blocks/CU).
//          HALF the barrier/vmcnt pairs: 16 MFMA : 12 ds_read per region.
//          Race-free: STAGE(it+2) targets buffer (it-1)%3 and is issued
//          after SBAR(it); every wave at SBAR(it) has issued compute(it-1)
//          MFMAs => (in-order issue + lgkm waits) its ds_reads retired.
// C[M,N] = A[M,K] * B[K,N] (+bias[M], opt relu). A row-major, BT=[N][K].
// Tile 128(M) x 64(N), 256 threads = 4 waves (2x2, wave-tile 64x32).
// Grid is ALWAYS (16,16,z): requires M=2048, N=1024. XCD-contiguous remap.
// CT_OUT=1: store C^T bf16 [N][M].  CT_OUT=0: store C fp32 [M][N].
// NA=3 (QKV): grid.z = b*3+which; which==0 scales output by 0.125 (q/sqrt(D));
//             which==2 stores NORMAL orientation bf16 [b][M][N] into Cb2.
// ---------------------------------------------------------------------------
template<int RELU, int CT_OUT, int NA, int BUFS>
__global__ __launch_bounds__(256) void gemm_bt(
    const u16* __restrict__ A0, const u16* __restrict__ A1, const u16* __restrict__ A2,
    const float* __restrict__ bias0, const float* __restrict__ bias1, const float* __restrict__ bias2,
    const u16* __restrict__ BTb, void* __restrict__ Cb, void* __restrict__ Cb2,
    int M, int N, int K, size_t sBT, size_t sC, size_t sWhich)
{
    const int z = blockIdx.z;
    const int which = (NA == 3) ? (z % 3) : 0;
    const int b     = (NA == 3) ? (z / 3) : z;
    const u16* __restrict__ A = (which == 0) ? A0 : (which == 1) ? A1 : A2;
    const float* __restrict__ bias = (which == 0) ? bias0 : (which == 1) ? bias1 : bias2;
    const u16* __restrict__ BT = BTb + (size_t)b * sBT;

    // XCD-contiguous tile remap: XCD k (= lin%8) owns 2 N-columns x all 16 M-tiles
    const int lin  = blockIdx.x + (blockIdx.y << 4);
    const int lin2 = ((lin & 7) << 5) + (lin >> 3);
    const int n0 = (lin2 >> 4) * 64;
    const int m0 = (lin2 & 15) * 128;

    constexpr int BKv = (BUFS == 3) ? 64 : 32;
    __shared__ u16 lA[BUFS * 128 * BKv];
    __shared__ u16 lB[BUFS * 64 * BKv];

    const int t = threadIdx.x, lane = t & 63, wave = t >> 6;
    const int wm = (wave >> 1) * 64, wn = (wave & 1) * 32;
    const int rl = lane & 15, kh = lane >> 4;

    fx4 acc[4][2];
    #pragma unroll
    for (int i = 0; i < 4; ++i)
        #pragma unroll
        for (int j = 0; j < 2; ++j) acc[i][j] = (fx4){0.f, 0.f, 0.f, 0.f};

    const int NT = K / BKv;

    if (BUFS == 3) {
        // ===== BK=64 path =====
        // staging: A 1024 16B-slots (4/thread), B 512 slots (2/thread).
        // slot s -> row s>>3, chunk-pos s&7; src chunk = pos ^ (row&7)
        const u16* gAp[4]; int dA[4];
        #pragma unroll
        for (int i = 0; i < 4; ++i) {
            int s = t + i * 256, row = s >> 3, src = (s & 7) ^ (row & 7);
            dA[i] = s * 8;
            gAp[i] = A + (size_t)(m0 + row) * K + src * 8;
        }
        const u16* gBp[2]; int dB[2];
        #pragma unroll
        for (int i = 0; i < 2; ++i) {
            int s = t + i * 256, row = s >> 3, src = (s & 7) ^ (row & 7);
            dB[i] = s * 8;
            gBp[i] = BT + (size_t)(n0 + row) * K + src * 8;
        }
        // frag offsets: half h, k-chunk c = h*4+kh; row r -> r*64 + ((c^(r&7))*8)
        int aoff[2][4], boff[2][2];
        #pragma unroll
        for (int h = 0; h < 2; ++h) {
            #pragma unroll
            for (int f = 0; f < 4; ++f) {
                int ra = wm + f * 16 + rl;
                aoff[h][f] = ra * 64 + (((h * 4 + kh) ^ (ra & 7)) * 8);
            }
            #pragma unroll
            for (int f = 0; f < 2; ++f) {
                int rb = wn + f * 16 + rl;
                boff[h][f] = rb * 64 + (((h * 4 + kh) ^ (rb & 7)) * 8);
            }
        }
#define STAGE64(BF, K0) do { \
        gld16(gAp[0] + (K0), &lA[(BF) * 128 * 64 + dA[0]]); \
        gld16(gAp[1] + (K0), &lA[(BF) * 128 * 64 + dA[1]]); \
        gld16(gAp[2] + (K0), &lA[(BF) * 128 * 64 + dA[2]]); \
        gld16(gAp[3] + (K0), &lA[(BF) * 128 * 64 + dA[3]]); \
        gld16(gBp[0] + (K0), &lB[(BF) * 64 * 64 + dB[0]]); \
        gld16(gBp[1] + (K0), &lB[(BF) * 64 * 64 + dB[1]]); } while (0)

        STAGE64(0, 0); STAGE64(1, 64);
        int bcur = 0, bst = 2;
        for (int it = 0; it < NT; ++it) {
            if (it + 1 < NT) { WAIT_VM(6); } else { WAIT_VM(0); }
            SBAR(); SFENCE();
            if (it + 2 < NT) STAGE64(bst, (it + 2) << 6);
            const u16* bA_ = &lA[bcur * 128 * 64];
            const u16* bB_ = &lB[bcur * 64 * 64];
            __builtin_amdgcn_s_setprio(1);
            #pragma unroll
            for (int h = 0; h < 2; ++h) {
                bfx8 af[4], bfr[2];
                #pragma unroll
                for (int f = 0; f < 4; ++f) af[f] = *(const bfx8*)&bA_[aoff[h][f]];
                #pragma unroll
                for (int f = 0; f < 2; ++f) bfr[f] = *(const bfx8*)&bB_[boff[h][f]];
                #pragma unroll
                for (int fm = 0; fm < 4; ++fm)
                    #pragma unroll
                    for (int fn = 0; fn < 2; ++fn)
                        acc[fm][fn] = MFMA16(af[fm], bfr[fn], acc[fm][fn], 0, 0, 0);
            }
            __builtin_amdgcn_s_setprio(0);
            if (++bcur == 3) bcur = 0;
            if (++bst == 3) bst = 0;
        }
#undef STAGE64
    } else {
        // ===== BK=32 paths (R16 verbatim) =====
        const int sA0 = t, sA1 = t + 256, sB = t;
        const int rA0 = sA0 >> 2, cA0 = (sA0 & 3) ^ ((rA0 >> 1) & 3);
        const int rA1 = sA1 >> 2, cA1 = (sA1 & 3) ^ ((rA1 >> 1) & 3);
        const int rB  = sB  >> 2, cB  = (sB  & 3) ^ ((rB  >> 1) & 3);
        const u16* gA0 = A  + (size_t)(m0 + rA0) * K + cA0 * 8;
        const u16* gA1 = A  + (size_t)(m0 + rA1) * K + cA1 * 8;
        const u16* gB0 = BT + (size_t)(n0 + rB) * K + cB * 8;

        int aoff[4], boff[2];
        #pragma unroll
        for (int f = 0; f < 4; ++f) {
            int ra = wm + f * 16 + rl;
            aoff[f] = ra * 32 + ((kh ^ ((ra >> 1) & 3)) * 8);
        }
        #pragma unroll
        for (int f = 0; f < 2; ++f) {
            int rb = wn + f * 16 + rl;
            boff[f] = rb * 32 + ((kh ^ ((rb >> 1) & 3)) * 8);
        }

#define STAGE32(BF, K0) do { \
        gld16(gA0 + (K0), &lA[(BF) * 128 * 32 + sA0 * 8]); \
        gld16(gA1 + (K0), &lA[(BF) * 128 * 32 + sA1 * 8]); \
        gld16(gB0 + (K0), &lB[(BF) * 64 * 32 + sB * 8]); } while (0)

#define COMPUTE32(BF) do { \
        const u16* bA_ = &lA[(BF) * 128 * 32]; \
        const u16* bB_ = &lB[(BF) * 64 * 32]; \
        bfx8 af[4], bfr[2]; \
        af[0] = *(const bfx8*)&bA_[aoff[0]]; \
        af[1] = *(const bfx8*)&bA_[aoff[1]]; \
        af[2] = *(const bfx8*)&bA_[aoff[2]]; \
        af[3] = *(const bfx8*)&bA_[aoff[3]]; \
        bfr[0] = *(const bfx8*)&bB_[boff[0]]; \
        bfr[1] = *(const bfx8*)&bB_[boff[1]]; \
        __builtin_amdgcn_s_setprio(1); \
        _Pragma("unroll") \
        for (int fm = 0; fm < 4; ++fm) \
            _Pragma("unroll") \
            for (int fn = 0; fn < 2; ++fn) \
                acc[fm][fn] = MFMA16(af[fm], bfr[fn], acc[fm][fn], 0, 0, 0); \
        __builtin_amdgcn_s_setprio(0); } while (0)

        if (BUFS == 6) {
            STAGE32(0, 0); STAGE32(1, 32); STAGE32(2, 64);
            WAIT_VM(6); SBAR(); SFENCE();
            int bcur = 0, bpre = 3;
            for (int it = 0; it < NT; ++it) {
                if (it + 3 < NT) {
                    STAGE32(bpre, (it + 3) << 5);
                    WAIT_VM(9);
                } else if (it + 2 < NT) {
                    WAIT_VM(6);
                } else if (it + 1 < NT) {
                    WAIT_VM(3);
                } else {
                    WAIT_VM(0);
                }
                SBAR(); SFENCE();
                COMPUTE32(bcur);
                if (++bcur == 6) bcur = 0;
                if (++bpre == 6) bpre = 0;
            }
        } else {
            STAGE32(0, 0); STAGE32(1, 32); STAGE32(2, 64);
            for (int it = 0; it < NT; ++it) {
                const int rem = NT - 1 - it;
                if (rem >= 2) { WAIT_VM(6); }
                else if (rem == 1) { WAIT_VM(3); }
                else { WAIT_VM(0); }
                SBAR(); SFENCE();
                if (it + 3 < NT) STAGE32((it + 3) & 3, (it + 3) << 5);
                COMPUTE32(it & 3);
            }
        }
#undef STAGE32
#undef COMPUTE32
    }

    if (NA == 3 && which == 2) {
        // v: store normal orientation bf16 [b][M][N]
        u16* Vn = (u16*)Cb2 + (size_t)b * (size_t)M * N;
        #pragma unroll
        for (int fm = 0; fm < 4; ++fm) {
            int mg = m0 + wm + fm * 16 + kh * 4;
            #pragma unroll
            for (int fn = 0; fn < 2; ++fn) {
                int ng = n0 + wn + fn * 16 + rl;
                #pragma unroll
                for (int r = 0; r < 4; ++r)
                    Vn[(size_t)(mg + r) * N + ng] = f2b(acc[fm][fn][r] + bias[mg + r]);
            }
        }
    } else if (CT_OUT) {
        const float sc = (NA == 3 && which == 0) ? 0.125f : 1.0f;
        u16* CT = (u16*)Cb + (size_t)which * sWhich + (size_t)b * sC;
        #pragma unroll
        for (int fm = 0; fm < 4; ++fm) {
            int mg = m0 + wm + fm * 16 + kh * 4;
            float bi0 = bias[mg], bi1 = bias[mg + 1], bi2 = bias[mg + 2], bi3 = bias[mg + 3];
            #pragma unroll
            for (int fn = 0; fn < 2; ++fn) {
                int ng = n0 + wn + fn * 16 + rl;
                float v0 = (acc[fm][fn][0] + bi0) * sc;
                float v1 = (acc[fm][fn][1] + bi1) * sc;
                float v2 = (acc[fm][fn][2] + bi2) * sc;
                float v3 = (acc[fm][fn][3] + bi3) * sc;
                if (RELU) {
                    v0 = fmaxf(v0, 0.f); v1 = fmaxf(v1, 0.f);
                    v2 = fmaxf(v2, 0.f); v3 = fmaxf(v3, 0.f);
                }
                us4 o = { f2b(v0), f2b(v1), f2b(v2), f2b(v3) };
                *(us4*)(CT + (size_t)ng * M + mg) = o;
            }
        }
    } else {
        float* C = (float*)Cb + (size_t)b * sC;
        #pragma unroll
        for (int fm = 0; fm < 4; ++fm) {
            int mg = m0 + wm + fm * 16 + kh * 4;
            #pragma unroll
            for (int fn = 0; fn < 2; ++fn) {
                int ng = n0 + wn + fn * 16 + rl;
                #pragma unroll
                for (int r = 0; r < 4; ++r) {
                    float v = acc[fm][fn][r] + bias[mg + r];
                    if (RELU) v = fmaxf(v, 0.f);
                    C[(size_t)(mg + r) * N + ng] = v;
                }
            }
        }
    }
}

// ---------------------------------------------------------------------------
// Pass A (BANDED +-1 tile, W=64): S[l] = sum_{m in tiles [lt-1,lt+1]}
// exp(att[l,m] - |l-m|/8). Verified numerically free in R12/R13.
// Block = 64 l-rows of one (b,h). grid (16, B*H). Depth-2 prefetch.
// ---------------------------------------------------------------------------
__global__ __launch_bounds__(256) void attn_stats(
    const u16* __restrict__ qT, const u16* __restrict__ kT,
    float* __restrict__ rinv)
{
    const int lt = blockIdx.x;
    const int bh = blockIdx.y;
    const int b = bh >> 5, h = bh & 31;
    const size_t base = (size_t)b * L * AF + h * DH;

    const int mlo = lt < 1 ? 0 : lt - 1;
    const int mhi = lt > 14 ? 15 : lt + 1;
    const int NTW = mhi - mlo + 1;   // 2..3 always

    __shared__ u16 lq[64 * 64];
    __shared__ u16 lk[4][64 * 64];
    __shared__ float sS[4][64];

    const int t = threadIdx.x, lane = t & 63, wave = t >> 6;
    const int rl = lane & 15, g = lane >> 4;

    const int s0 = t, s1 = t + 256;
    const int r0 = s0 >> 3, cs0 = (s0 & 7) ^ (r0 & 7);
    const int r1 = s1 >> 3, cs1 = (s1 & 7) ^ (r1 & 7);

    const u16* gk0 = kT + base + (size_t)(mlo * 64 + r0) * AF + cs0 * 8;
    const u16* gk1 = kT + base + (size_t)(mlo * 64 + r1) * AF + cs1 * 8;

    gld16(qT + base + (size_t)(lt * 64 + r0) * AF + cs0 * 8, lq + s0 * 8);
    gld16(qT + base + (size_t)(lt * 64 + r1) * AF + cs1 * 8, lq + s1 * 8);
    gld16(gk0, &lk[0][s0 * 8]);
    gld16(gk1, &lk[0][s1 * 8]);
    gld16(gk0 + (size_t)64 * AF, &lk[1][s0 * 8]);
    gld16(gk1 + (size_t)64 * AF, &lk[1][s1 * 8]);
    WAIT_VM(2); SBAR(); SFENCE();    // q + k0 landed

    const int rmr = wave * 16 + rl;
    const int akoff0 = rmr * 64 + ((g ^ (rmr & 7)) * 8);
    const int akoff1 = rmr * 64 + (((g + 4) ^ (rmr & 7)) * 8);
    bfx8 qf0[4], qf1[4];
    #pragma unroll
    for (int f = 0; f < 4; ++f) {
        int rq = f * 16 + rl;
        qf0[f] = *(const bfx8*)&lq[rq * 64 + ((g ^ (rq & 7)) * 8)];
        qf1[f] = *(const bfx8*)&lq[rq * 64 + (((g + 4) ^ (rq & 7)) * 8)];
    }

    float Sx[4] = {0.f, 0.f, 0.f, 0.f};
    for (int i = 0; i < NTW; ++i) {
        if (i + 2 < NTW) {
            const int bf = (i + 2) & 3;
            gld16(gk0 + (size_t)(i + 2) * 64 * AF, &lk[bf][s0 * 8]);
            gld16(gk1 + (size_t)(i + 2) * 64 * AF, &lk[bf][s1 * 8]);
            WAIT_VM(4);
        } else if (i + 1 < NTW) {
            WAIT_VM(2);
        } else {
            WAIT_VM(0);
        }
        SBAR(); SFENCE();
        const u16* kb = lk[i & 3];
        bfx8 ak0 = *(const bfx8*)&kb[akoff0];
        bfx8 ak1 = *(const bfx8*)&kb[akoff1];
        const float mb = (float)((mlo + i) * 64 + wave * 16 + g * 4);
        #pragma unroll
        for (int fn = 0; fn < 4; ++fn) {
            fx4 att = (fx4){0.f, 0.f, 0.f, 0.f};
            att = MFMA16(ak0, qf0[fn], att, 0, 0, 0);
            att = MFMA16(ak1, qf1[fn], att, 0, 0, 0);
            const float lgf = (float)(lt * 64 + fn * 16 + rl);
            float e0 = __expf(att[0] - 0.125f * fabsf(lgf - mb));
            float e1 = __expf(att[1] - 0.125f * fabsf(lgf - (mb + 1.f)));
            float e2 = __expf(att[2] - 0.125f * fabsf(lgf - (mb + 2.f)));
            float e3 = __expf(att[3] - 0.125f * fabsf(lgf - (mb + 3.f)));
            Sx[fn] += (e0 + e1) + (e2 + e3);
        }
    }
    #pragma unroll
    for (int fn = 0; fn < 4; ++fn) {
        float s_ = Sx[fn];
        s_ += __shfl_xor(s_, 16);
        s_ += __shfl_xor(s_, 32);
        if (lane < 16) sS[wave][fn * 16 + rl] = s_;
    }
    __syncthreads();
    if (t < 64) {
        float s_ = sS[0][t] + sS[1][t] + sS[2][t] + sS[3][t];
        rinv[(size_t)bh * L + lt * 64 + t] = 1.0f / s_;
    }
}

// ---------------------------------------------------------------------------
// Pass B (BANDED +-1 tile): O[d,m] = sum over l-tiles [mt-1, mt] of
// v[d,l]*w[l,m]; h = relu(O) -> hT[b][m][h*64+d]. grid (16, B*H).
// ---------------------------------------------------------------------------
__global__ __launch_bounds__(256) void attn_pv(
    const u16* __restrict__ qT, const u16* __restrict__ kT, const u16* __restrict__ v,
    const float* __restrict__ rinv, u16* __restrict__ hT)
{
    const int mt = blockIdx.x;
    const int bh = blockIdx.y;
    const int b = bh >> 5, h = bh & 31;
    const size_t qkbase = (size_t)b * L * AF + h * DH;
    const size_t vbase  = ((size_t)b * AF + h * DH) * L;
    const size_t rbase  = (size_t)bh * L;

    const int ltlo = mt < 1 ? 0 : mt - 1;
    const int NI = mt - ltlo + 1;    // 1..2
    const int m0 = mt * 64;

    __shared__ u16 lkt[64 * 64];
    __shared__ u16 lqt[2][64 * 64], lv[2][64 * 64];
    __shared__ u16 lw[64 * 68];   // wT[m][l], pad 68

    const int t = threadIdx.x, lane = t & 63, wave = t >> 6;
    const int rl = lane & 15, g = lane >> 4;

    const int s0 = t, s1 = t + 256;
    const int r0 = s0 >> 3, cs0 = (s0 & 7) ^ (r0 & 7);
    const int r1 = s1 >> 3, cs1 = (s1 & 7) ^ (r1 & 7);

    const u16* gq0 = qT + qkbase + (size_t)(ltlo * 64 + r0) * AF + cs0 * 8;
    const u16* gq1 = qT + qkbase + (size_t)(ltlo * 64 + r1) * AF + cs1 * 8;
    const u16* gv0 = v + vbase + ltlo * 64 + (size_t)r0 * L + cs0 * 8;
    const u16* gv1 = v + vbase + ltlo * 64 + (size_t)r1 * L + cs1 * 8;

    const int rmr = wave * 16 + rl;     // phase-1 A rows (m), phase-2 A rows (d)
    const int toff0 = rmr * 64 + ((g ^ (rmr & 7)) * 8);
    const int toff1 = rmr * 64 + (((g + 4) ^ (rmr & 7)) * 8);
    int qoff0[4], qoff1[4];
    #pragma unroll
    for (int f = 0; f < 4; ++f) {
        int rq = f * 16 + rl;
        qoff0[f] = rq * 64 + ((g ^ (rq & 7)) * 8);
        qoff1[f] = rq * 64 + (((g + 4) ^ (rq & 7)) * 8);
    }

    // prologue: K-tile + first q/v tile
    gld16(kT + qkbase + (size_t)(m0 + r0) * AF + cs0 * 8, lkt + s0 * 8);
    gld16(kT + qkbase + (size_t)(m0 + r1) * AF + cs1 * 8, lkt + s1 * 8);
    gld16(gq0, &lqt[0][s0 * 8]);
    gld16(gq1, &lqt[0][s1 * 8]);
    gld16(gv0, &lv[0][s0 * 8]);
    gld16(gv1, &lv[0][s1 * 8]);
    WAIT_VM(0); SBAR(); SFENCE();

    fx4 oa[4];
    #pragma unroll
    for (int f = 0; f < 4; ++f) oa[f] = (fx4){0.f, 0.f, 0.f, 0.f};

    int cur = 0;
    for (int i = 0; i < NI; ++i) {
        const int lt = ltlo + i;
        if (i + 1 < NI) {   // prefetch next q/v tile into the other buffer
            gld16(gq0 + (size_t)(i + 1) * 64 * AF, &lqt[cur ^ 1][s0 * 8]);
            gld16(gq1 + (size_t)(i + 1) * 64 * AF, &lqt[cur ^ 1][s1 * 8]);
            gld16(gv0 + (i + 1) * 64, &lv[cur ^ 1][s0 * 8]);
            gld16(gv1 + (i + 1) * 64, &lv[cur ^ 1][s1 * 8]);
        }
        // phase 1: att^T[m][l] = mfma(kT rows m, qT rows l) -> weights in lw
        bfx8 ak0 = *(const bfx8*)&lkt[toff0];
        bfx8 ak1 = *(const bfx8*)&lkt[toff1];
        const u16* qb = lqt[cur];
        #pragma unroll
        for (int fn = 0; fn < 4; ++fn) {
            bfx8 q0 = *(const bfx8*)&qb[qoff0[fn]];
            bfx8 q1 = *(const bfx8*)&qb[qoff1[fn]];
            fx4 att = (fx4){0.f, 0.f, 0.f, 0.f};
            att = MFMA16(ak0, q0, att, 0, 0, 0);
            att = MFMA16(ak1, q1, att, 0, 0, 0);
            const int lg = lt * 64 + fn * 16 + rl;
            float ri = rinv[rbase + lg];
            const float db = (float)(lg - (m0 + wave * 16 + g * 4));
            #pragma unroll
            for (int r = 0; r < 4; ++r) {
                int mloc = wave * 16 + g * 4 + r;
                float s = att[r] - 0.125f * fabsf(db - (float)r);
                float w = (lg <= m0 + mloc) ? __expf(s) * ri : 0.f;
                lw[mloc * 68 + fn * 16 + rl] = f2b(w);
            }
        }
        WAIT_LGKM0(); SBAR(); SFENCE();   // lw visible; prefetch stays in flight

        // phase 2: O[d][m] += mfma(v rows d, wT rows m)
        const u16* vb = lv[cur];
        bfx8 av0 = *(const bfx8*)&vb[toff0];
        bfx8 av1 = *(const bfx8*)&vb[toff1];
        #pragma unroll
        for (int fn = 0; fn < 4; ++fn) {
            const u16* wrow = &lw[(fn * 16 + rl) * 68];
            union { bfx8 f; bfx4 hh[2]; } w0, w1;
            w0.hh[0] = *(const bfx4*)&wrow[g * 8];
            w0.hh[1] = *(const bfx4*)&wrow[g * 8 + 4];
            w1.hh[0] = *(const bfx4*)&wrow[(g + 4) * 8];
            w1.hh[1] = *(const bfx4*)&wrow[(g + 4) * 8 + 4];
            oa[fn] = MFMA16(av0, w0.f, oa[fn], 0, 0, 0);
            oa[fn] = MFMA16(av1, w1.f, oa[fn], 0, 0, 0);
        }
        WAIT_VM(0); WAIT_LGKM0(); SBAR(); SFENCE();   // next tile landed; reads done
        cur ^= 1;
    }

    // epilogue: relu, C^T store -> hT[b][m][h*64+d]
    #pragma unroll
    for (int fn = 0; fn < 4; ++fn) {
        int mg = m0 + fn * 16 + rl;
        int cg = h * DH + wave * 16 + g * 4;
        us4 o = { f2b(fmaxf(oa[fn][0], 0.f)), f2b(fmaxf(oa[fn][1], 0.f)),
                  f2b(fmaxf(oa[fn][2], 0.f)), f2b(fmaxf(oa[fn][3], 0.f)) };
        *(us4*)(hT + ((size_t)b * L + mg) * AF + cg) = o;
    }
}

// ---------------------------------------------------------------------------
extern "C" void kernel_launch(void* const* d_in, const int* in_sizes, int n_in,
                              void* d_out, int out_size, void* d_ws, size_t ws_size,
                              hipStream_t stream)
{
    (void)in_sizes; (void)n_in; (void)out_size; (void)ws_size;
    const float* x  = (const float*)d_in[0];
    const float* Wq = (const float*)d_in[1];
    const float* bq = (const float*)d_in[2];
    const float* Wk = (const float*)d_in[3];
    const float* bk = (const float*)d_in[4];
    const float* Wv = (const float*)d_in[5];
    const float* bv = (const float*)d_in[6];
    const float* W1 = (const float*)d_in[7];
    const float* b1 = (const float*)d_in[8];
    const float* W2 = (const float*)d_in[9];
    const float* b2 = (const float*)d_in[10];

    u16* wsp = (u16*)d_ws;
    size_t o = 0;
    u16* xT  = wsp + o; o += (size_t)NB * L * CIN;
    u16* qT  = wsp + o; o += (size_t)NB * L * AF;   // q (pre-scaled by 1/8), [b][l][af]
    u16* kT  = wsp + o; o += (size_t)NB * L * AF;   // must follow qT (which*sWhich)
    u16* vdm = wsp + o; o += (size_t)NB * AF * L;   // v normal orientation [b][af][l]
    u16* hT  = wsp + o; o += (size_t)NB * L * AF;
    u16* z1T = wsp + o; o += (size_t)NB * L * AF;
    u16* Wqb = wsp + o; o += (size_t)AF * CIN;
    u16* Wkb = wsp + o; o += (size_t)AF * CIN;
    u16* Wvb = wsp + o; o += (size_t)AF * CIN;
    u16* W1b = wsp + o; o += (size_t)AF * AF;
    u16* W2b = wsp + o; o += (size_t)AF * AF;
    float* rinv = (float*)(wsp + o); o += (size_t)NB * NH * L * 2;

    dim3 blk(256);

    prep<<<dim3(512, 1, 6), blk, 0, stream>>>(x, Wq, Wk, Wv, W1, W2,
                                              xT, Wqb, Wkb, Wvb, W1b, W2b);

    // QKV: qT/kT = (W? * x)^T (q scaled 1/8); v -> vdm normal orientation
    // BUFS=3 (BK=64): half the barrier pairs -- A-arm of this round's test.
    gemm_bt<0, 1, 3, 3><<<dim3(16, 16, NB * 3), blk, 0, stream>>>(
        Wqb, Wkb, Wvb, bq, bk, bv, xT, qT, vdm,
        AF, L, CIN, (size_t)L * CIN, (size_t)L * AF, (size_t)NB * L * AF);

    attn_stats<<<dim3(16, NB * NH), blk, 0, stream>>>(qT, kT, rinv);
    attn_pv<<<dim3(16, NB * NH), blk, 0, stream>>>(qT, kT, vdm, rinv, hT);

    // z1T = relu(W1*h + b1)^T  -- BUFS=3 (BK=64) A-arm
    gemm_bt<1, 1, 1, 3><<<dim3(16, 16, NB), blk, 0, stream>>>(
        W1b, nullptr, nullptr, b1, nullptr, nullptr, hT, z1T, nullptr,
        AF, L, AF, (size_t)L * AF, (size_t)L * AF, 0);
    // out = W2*z1 + b2 (fp32 strided epilogue) -- BUFS=6 CONTROL (R16 config)
    gemm_bt<0, 0, 1, 6><<<dim3(16, 16, NB), blk, 0, stream>>>(
        W2b, nullptr, nullptr, b2, nullptr, nullptr, z1T, d_out, nullptr,
        AF, L, AF, (size_t)L * AF, (size_t)AF * L, 0);
}

// Round 18
// 131.331 us; speedup vs baseline: 1.0682x; 1.0217x over previous
//
#include <hip/hip_runtime.h>

#define L 1024
#define CIN 512
#define NH 32
#define DH 64
#define NB 2
#define AF 2048

typedef unsigned short u16;
typedef unsigned int u32;
typedef __attribute__((ext_vector_type(8))) short bfx8;   // 8 bf16 = 4 VGPR (MFMA A/B frag)
typedef __attribute__((ext_vector_type(4))) short bfx4;   // 8B half-frag
typedef __attribute__((ext_vector_type(4))) float fx4;    // MFMA C/D frag

struct __align__(8) us4 { u16 x, y, z, w; };

#define MFMA16 __builtin_amdgcn_mfma_f32_16x16x32_bf16
#define SBAR() __builtin_amdgcn_s_barrier()
#define SFENCE() __builtin_amdgcn_sched_barrier(0)
#define WAIT_VM(N) asm volatile("s_waitcnt vmcnt(" #N ")" ::: "memory")
#define WAIT_LGKM0() asm volatile("s_waitcnt lgkmcnt(0)" ::: "memory")

__device__ inline void gld16(const void* g, void* l) {
    __builtin_amdgcn_global_load_lds(
        (const __attribute__((address_space(1))) u32*)g,
        (__attribute__((address_space(3))) u32*)l, 16, 0, 0);
}

__device__ inline u16 f2b(float f) {
    union { float f; u32 u; } v; v.f = f;
    u32 u = v.u;
    return (u16)((u + 0x7fffu + ((u >> 16) & 1u)) >> 16);
}

// ---------------------------------------------------------------------------
// prep: all fp32->bf16 weight converts (z=0..4) + x transpose/convert (z=5).
// grid (512, 1, 6), block 256.
// ---------------------------------------------------------------------------
__global__ __launch_bounds__(256) void prep(
    const float* __restrict__ x,
    const float* __restrict__ Wq, const float* __restrict__ Wk, const float* __restrict__ Wv,
    const float* __restrict__ W1, const float* __restrict__ W2,
    u16* __restrict__ xT, u16* __restrict__ Wqb, u16* __restrict__ Wkb,
    u16* __restrict__ Wvb, u16* __restrict__ W1b, u16* __restrict__ W2b)
{
    __shared__ u16 tile[64][68];
    const int z = blockIdx.z;
    const int t = threadIdx.x;
    if (z < 5) {
        const float* in; u16* out; int n4;
        switch (z) {
            case 0: in = Wq; out = Wqb; n4 = AF * CIN / 4; break;
            case 1: in = Wk; out = Wkb; n4 = AF * CIN / 4; break;
            case 2: in = Wv; out = Wvb; n4 = AF * CIN / 4; break;
            case 3: in = W1; out = W1b; n4 = AF * AF / 4; break;
            default: in = W2; out = W2b; n4 = AF * AF / 4; break;
        }
        int i = blockIdx.x * 256 + t;
        for (; i < n4; i += 512 * 256) {
            float4 v = ((const float4*)in)[i];
            us4 o = { f2b(v.x), f2b(v.y), f2b(v.z), f2b(v.w) };
            ((us4*)out)[i] = o;
        }
    } else {
        const int bid = blockIdx.x;
        if (bid >= 256) return;
        const int c0 = (bid & 7) * 64, l0 = ((bid >> 3) & 15) * 64, b = bid >> 7;
        const int tr = t >> 4, tc4 = (t & 15) * 4;
        #pragma unroll
        for (int p = 0; p < 4; ++p) {
            int c = p * 16 + tr;
            float4 v = *(const float4*)(x + ((size_t)(b * CIN + c0 + c)) * L + l0 + tc4);
            tile[c][tc4 + 0] = f2b(v.x); tile[c][tc4 + 1] = f2b(v.y);
            tile[c][tc4 + 2] = f2b(v.z); tile[c][tc4 + 3] = f2b(v.w);
        }
        __syncthreads();
        #pragma unroll
        for (int p = 0; p < 4; ++p) {
            int l = p * 16 + tr;
            us4 o = { tile[tc4 + 0][l], tile[tc4 + 1][l], tile[tc4 + 2][l], tile[tc4 + 3][l] };
            *(us4*)(xT + ((size_t)(b * L + l0 + l)) * CIN + c0 + tc4) = o;
        }
    }
}

// ---------------------------------------------------------------------------
// MFMA GEMM, templated pipeline (BUFS selects schedule):
//  BUFS=3: BK=64, stage-after-barrier depth-2, 72 KB (2 blocks/CU).
//          HALF the barrier/vmcnt pairs: 16 MFMA : 12 ds_read per region.
//          Won R17 A/B on QKV+W1 (-4.3 us). Race-free: STAGE(it+2) targets
//          buffer (it-1)%3 and is issued after SBAR(it); every wave at
//          SBAR(it) has issued compute(it-1) MFMAs => ds_reads retired.
//  BUFS=6: BK=32, STAGE-before-waits depth-3, 72 KB (R6 schedule; fallback).
//  BUFS=4: BK=32, stage-after-barrier depth-3, 48 KB (3 blocks/CU).
// C[M,N] = A[M,K] * B[K,N] (+bias[M], opt relu). A row-major, BT=[N][K].
// Tile 128(M) x 64(N), 256 threads = 4 waves (2x2, wave-tile 64x32).
// Grid is ALWAYS (16,16,z): requires M=2048, N=1024. XCD-contiguous remap.
// CT_OUT=1: store C^T bf16 [N][M].  CT_OUT=0: store C fp32 [M][N].
// NA=3 (QKV): grid.z = b*3+which; which==0 scales output by 0.125 (q/sqrt(D));
//             which==2 stores NORMAL orientation bf16 [b][M][N] into Cb2.
// ---------------------------------------------------------------------------
template<int RELU, int CT_OUT, int NA, int BUFS>
__global__ __launch_bounds__(256) void gemm_bt(
    const u16* __restrict__ A0, const u16* __restrict__ A1, const u16* __restrict__ A2,
    const float* __restrict__ bias0, const float* __restrict__ bias1, const float* __restrict__ bias2,
    const u16* __restrict__ BTb, void* __restrict__ Cb, void* __restrict__ Cb2,
    int M, int N, int K, size_t sBT, size_t sC, size_t sWhich)
{
    const int z = blockIdx.z;
    const int which = (NA == 3) ? (z % 3) : 0;
    const int b     = (NA == 3) ? (z / 3) : z;
    const u16* __restrict__ A = (which == 0) ? A0 : (which == 1) ? A1 : A2;
    const float* __restrict__ bias = (which == 0) ? bias0 : (which == 1) ? bias1 : bias2;
    const u16* __restrict__ BT = BTb + (size_t)b * sBT;

    // XCD-contiguous tile remap: XCD k (= lin%8) owns 2 N-columns x all 16 M-tiles
    const int lin  = blockIdx.x + (blockIdx.y << 4);
    const int lin2 = ((lin & 7) << 5) + (lin >> 3);
    const int n0 = (lin2 >> 4) * 64;
    const int m0 = (lin2 & 15) * 128;

    constexpr int BKv = (BUFS == 3) ? 64 : 32;
    __shared__ u16 lA[BUFS * 128 * BKv];
    __shared__ u16 lB[BUFS * 64 * BKv];

    const int t = threadIdx.x, lane = t & 63, wave = t >> 6;
    const int wm = (wave >> 1) * 64, wn = (wave & 1) * 32;
    const int rl = lane & 15, kh = lane >> 4;

    fx4 acc[4][2];
    #pragma unroll
    for (int i = 0; i < 4; ++i)
        #pragma unroll
        for (int j = 0; j < 2; ++j) acc[i][j] = (fx4){0.f, 0.f, 0.f, 0.f};

    const int NT = K / BKv;

    if (BUFS == 3) {
        // ===== BK=64 path =====
        // staging: A 1024 16B-slots (4/thread), B 512 slots (2/thread).
        // slot s -> row s>>3, chunk-pos s&7; src chunk = pos ^ (row&7)
        const u16* gAp[4]; int dA[4];
        #pragma unroll
        for (int i = 0; i < 4; ++i) {
            int s = t + i * 256, row = s >> 3, src = (s & 7) ^ (row & 7);
            dA[i] = s * 8;
            gAp[i] = A + (size_t)(m0 + row) * K + src * 8;
        }
        const u16* gBp[2]; int dB[2];
        #pragma unroll
        for (int i = 0; i < 2; ++i) {
            int s = t + i * 256, row = s >> 3, src = (s & 7) ^ (row & 7);
            dB[i] = s * 8;
            gBp[i] = BT + (size_t)(n0 + row) * K + src * 8;
        }
        // frag offsets: half h, k-chunk c = h*4+kh; row r -> r*64 + ((c^(r&7))*8)
        int aoff[2][4], boff[2][2];
        #pragma unroll
        for (int h = 0; h < 2; ++h) {
            #pragma unroll
            for (int f = 0; f < 4; ++f) {
                int ra = wm + f * 16 + rl;
                aoff[h][f] = ra * 64 + (((h * 4 + kh) ^ (ra & 7)) * 8);
            }
            #pragma unroll
            for (int f = 0; f < 2; ++f) {
                int rb = wn + f * 16 + rl;
                boff[h][f] = rb * 64 + (((h * 4 + kh) ^ (rb & 7)) * 8);
            }
        }
#define STAGE64(BF, K0) do { \
        gld16(gAp[0] + (K0), &lA[(BF) * 128 * 64 + dA[0]]); \
        gld16(gAp[1] + (K0), &lA[(BF) * 128 * 64 + dA[1]]); \
        gld16(gAp[2] + (K0), &lA[(BF) * 128 * 64 + dA[2]]); \
        gld16(gAp[3] + (K0), &lA[(BF) * 128 * 64 + dA[3]]); \
        gld16(gBp[0] + (K0), &lB[(BF) * 64 * 64 + dB[0]]); \
        gld16(gBp[1] + (K0), &lB[(BF) * 64 * 64 + dB[1]]); } while (0)

        STAGE64(0, 0); STAGE64(1, 64);
        int bcur = 0, bst = 2;
        for (int it = 0; it < NT; ++it) {
            if (it + 1 < NT) { WAIT_VM(6); } else { WAIT_VM(0); }
            SBAR(); SFENCE();
            if (it + 2 < NT) STAGE64(bst, (it + 2) << 6);
            const u16* bA_ = &lA[bcur * 128 * 64];
            const u16* bB_ = &lB[bcur * 64 * 64];
            __builtin_amdgcn_s_setprio(1);
            #pragma unroll
            for (int h = 0; h < 2; ++h) {
                bfx8 af[4], bfr[2];
                #pragma unroll
                for (int f = 0; f < 4; ++f) af[f] = *(const bfx8*)&bA_[aoff[h][f]];
                #pragma unroll
                for (int f = 0; f < 2; ++f) bfr[f] = *(const bfx8*)&bB_[boff[h][f]];
                #pragma unroll
                for (int fm = 0; fm < 4; ++fm)
                    #pragma unroll
                    for (int fn = 0; fn < 2; ++fn)
                        acc[fm][fn] = MFMA16(af[fm], bfr[fn], acc[fm][fn], 0, 0, 0);
            }
            __builtin_amdgcn_s_setprio(0);
            if (++bcur == 3) bcur = 0;
            if (++bst == 3) bst = 0;
        }
#undef STAGE64
    } else {
        // ===== BK=32 paths (R16 verbatim) =====
        const int sA0 = t, sA1 = t + 256, sB = t;
        const int rA0 = sA0 >> 2, cA0 = (sA0 & 3) ^ ((rA0 >> 1) & 3);
        const int rA1 = sA1 >> 2, cA1 = (sA1 & 3) ^ ((rA1 >> 1) & 3);
        const int rB  = sB  >> 2, cB  = (sB  & 3) ^ ((rB  >> 1) & 3);
        const u16* gA0 = A  + (size_t)(m0 + rA0) * K + cA0 * 8;
        const u16* gA1 = A  + (size_t)(m0 + rA1) * K + cA1 * 8;
        const u16* gB0 = BT + (size_t)(n0 + rB) * K + cB * 8;

        int aoff[4], boff[2];
        #pragma unroll
        for (int f = 0; f < 4; ++f) {
            int ra = wm + f * 16 + rl;
            aoff[f] = ra * 32 + ((kh ^ ((ra >> 1) & 3)) * 8);
        }
        #pragma unroll
        for (int f = 0; f < 2; ++f) {
            int rb = wn + f * 16 + rl;
            boff[f] = rb * 32 + ((kh ^ ((rb >> 1) & 3)) * 8);
        }

#define STAGE32(BF, K0) do { \
        gld16(gA0 + (K0), &lA[(BF) * 128 * 32 + sA0 * 8]); \
        gld16(gA1 + (K0), &lA[(BF) * 128 * 32 + sA1 * 8]); \
        gld16(gB0 + (K0), &lB[(BF) * 64 * 32 + sB * 8]); } while (0)

#define COMPUTE32(BF) do { \
        const u16* bA_ = &lA[(BF) * 128 * 32]; \
        const u16* bB_ = &lB[(BF) * 64 * 32]; \
        bfx8 af[4], bfr[2]; \
        af[0] = *(const bfx8*)&bA_[aoff[0]]; \
        af[1] = *(const bfx8*)&bA_[aoff[1]]; \
        af[2] = *(const bfx8*)&bA_[aoff[2]]; \
        af[3] = *(const bfx8*)&bA_[aoff[3]]; \
        bfr[0] = *(const bfx8*)&bB_[boff[0]]; \
        bfr[1] = *(const bfx8*)&bB_[boff[1]]; \
        __builtin_amdgcn_s_setprio(1); \
        _Pragma("unroll") \
        for (int fm = 0; fm < 4; ++fm) \
            _Pragma("unroll") \
            for (int fn = 0; fn < 2; ++fn) \
                acc[fm][fn] = MFMA16(af[fm], bfr[fn], acc[fm][fn], 0, 0, 0); \
        __builtin_amdgcn_s_setprio(0); } while (0)

        if (BUFS == 6) {
            STAGE32(0, 0); STAGE32(1, 32); STAGE32(2, 64);
            WAIT_VM(6); SBAR(); SFENCE();
            int bcur = 0, bpre = 3;
            for (int it = 0; it < NT; ++it) {
                if (it + 3 < NT) {
                    STAGE32(bpre, (it + 3) << 5);
                    WAIT_VM(9);
                } else if (it + 2 < NT) {
                    WAIT_VM(6);
                } else if (it + 1 < NT) {
                    WAIT_VM(3);
                } else {
                    WAIT_VM(0);
                }
                SBAR(); SFENCE();
                COMPUTE32(bcur);
                if (++bcur == 6) bcur = 0;
                if (++bpre == 6) bpre = 0;
            }
        } else {
            STAGE32(0, 0); STAGE32(1, 32); STAGE32(2, 64);
            for (int it = 0; it < NT; ++it) {
                const int rem = NT - 1 - it;
                if (rem >= 2) { WAIT_VM(6); }
                else if (rem == 1) { WAIT_VM(3); }
                else { WAIT_VM(0); }
                SBAR(); SFENCE();
                if (it + 3 < NT) STAGE32((it + 3) & 3, (it + 3) << 5);
                COMPUTE32(it & 3);
            }
        }
#undef STAGE32
#undef COMPUTE32
    }

    if (NA == 3 && which == 2) {
        // v: store normal orientation bf16 [b][M][N]
        u16* Vn = (u16*)Cb2 + (size_t)b * (size_t)M * N;
        #pragma unroll
        for (int fm = 0; fm < 4; ++fm) {
            int mg = m0 + wm + fm * 16 + kh * 4;
            #pragma unroll
            for (int fn = 0; fn < 2; ++fn) {
                int ng = n0 + wn + fn * 16 + rl;
                #pragma unroll
                for (int r = 0; r < 4; ++r)
                    Vn[(size_t)(mg + r) * N + ng] = f2b(acc[fm][fn][r] + bias[mg + r]);
            }
        }
    } else if (CT_OUT) {
        const float sc = (NA == 3 && which == 0) ? 0.125f : 1.0f;
        u16* CT = (u16*)Cb + (size_t)which * sWhich + (size_t)b * sC;
        #pragma unroll
        for (int fm = 0; fm < 4; ++fm) {
            int mg = m0 + wm + fm * 16 + kh * 4;
            float bi0 = bias[mg], bi1 = bias[mg + 1], bi2 = bias[mg + 2], bi3 = bias[mg + 3];
            #pragma unroll
            for (int fn = 0; fn < 2; ++fn) {
                int ng = n0 + wn + fn * 16 + rl;
                float v0 = (acc[fm][fn][0] + bi0) * sc;
                float v1 = (acc[fm][fn][1] + bi1) * sc;
                float v2 = (acc[fm][fn][2] + bi2) * sc;
                float v3 = (acc[fm][fn][3] + bi3) * sc;
                if (RELU) {
                    v0 = fmaxf(v0, 0.f); v1 = fmaxf(v1, 0.f);
                    v2 = fmaxf(v2, 0.f); v3 = fmaxf(v3, 0.f);
                }
                us4 o = { f2b(v0), f2b(v1), f2b(v2), f2b(v3) };
                *(us4*)(CT + (size_t)ng * M + mg) = o;
            }
        }
    } else {
        float* C = (float*)Cb + (size_t)b * sC;
        #pragma unroll
        for (int fm = 0; fm < 4; ++fm) {
            int mg = m0 + wm + fm * 16 + kh * 4;
            #pragma unroll
            for (int fn = 0; fn < 2; ++fn) {
                int ng = n0 + wn + fn * 16 + rl;
                #pragma unroll
                for (int r = 0; r < 4; ++r) {
                    float v = acc[fm][fn][r] + bias[mg + r];
                    if (RELU) v = fmaxf(v, 0.f);
                    C[(size_t)(mg + r) * N + ng] = v;
                }
            }
        }
    }
}

// ---------------------------------------------------------------------------
// Pass A (BANDED +-1 tile, W=64): S[l] = sum_{m in tiles [lt-1,lt+1]}
// exp(att[l,m] - |l-m|/8). Verified numerically free in R12/R13.
// Block = 64 l-rows of one (b,h). grid (16, B*H). Depth-2 prefetch.
// ---------------------------------------------------------------------------
__global__ __launch_bounds__(256) void attn_stats(
    const u16* __restrict__ qT, const u16* __restrict__ kT,
    float* __restrict__ rinv)
{
    const int lt = blockIdx.x;
    const int bh = blockIdx.y;
    const int b = bh >> 5, h = bh & 31;
    const size_t base = (size_t)b * L * AF + h * DH;

    const int mlo = lt < 1 ? 0 : lt - 1;
    const int mhi = lt > 14 ? 15 : lt + 1;
    const int NTW = mhi - mlo + 1;   // 2..3 always

    __shared__ u16 lq[64 * 64];
    __shared__ u16 lk[4][64 * 64];
    __shared__ float sS[4][64];

    const int t = threadIdx.x, lane = t & 63, wave = t >> 6;
    const int rl = lane & 15, g = lane >> 4;

    const int s0 = t, s1 = t + 256;
    const int r0 = s0 >> 3, cs0 = (s0 & 7) ^ (r0 & 7);
    const int r1 = s1 >> 3, cs1 = (s1 & 7) ^ (r1 & 7);

    const u16* gk0 = kT + base + (size_t)(mlo * 64 + r0) * AF + cs0 * 8;
    const u16* gk1 = kT + base + (size_t)(mlo * 64 + r1) * AF + cs1 * 8;

    gld16(qT + base + (size_t)(lt * 64 + r0) * AF + cs0 * 8, lq + s0 * 8);
    gld16(qT + base + (size_t)(lt * 64 + r1) * AF + cs1 * 8, lq + s1 * 8);
    gld16(gk0, &lk[0][s0 * 8]);
    gld16(gk1, &lk[0][s1 * 8]);
    gld16(gk0 + (size_t)64 * AF, &lk[1][s0 * 8]);
    gld16(gk1 + (size_t)64 * AF, &lk[1][s1 * 8]);
    WAIT_VM(2); SBAR(); SFENCE();    // q + k0 landed

    const int rmr = wave * 16 + rl;
    const int akoff0 = rmr * 64 + ((g ^ (rmr & 7)) * 8);
    const int akoff1 = rmr * 64 + (((g + 4) ^ (rmr & 7)) * 8);
    bfx8 qf0[4], qf1[4];
    #pragma unroll
    for (int f = 0; f < 4; ++f) {
        int rq = f * 16 + rl;
        qf0[f] = *(const bfx8*)&lq[rq * 64 + ((g ^ (rq & 7)) * 8)];
        qf1[f] = *(const bfx8*)&lq[rq * 64 + (((g + 4) ^ (rq & 7)) * 8)];
    }

    float Sx[4] = {0.f, 0.f, 0.f, 0.f};
    for (int i = 0; i < NTW; ++i) {
        if (i + 2 < NTW) {
            const int bf = (i + 2) & 3;
            gld16(gk0 + (size_t)(i + 2) * 64 * AF, &lk[bf][s0 * 8]);
            gld16(gk1 + (size_t)(i + 2) * 64 * AF, &lk[bf][s1 * 8]);
            WAIT_VM(4);
        } else if (i + 1 < NTW) {
            WAIT_VM(2);
        } else {
            WAIT_VM(0);
        }
        SBAR(); SFENCE();
        const u16* kb = lk[i & 3];
        bfx8 ak0 = *(const bfx8*)&kb[akoff0];
        bfx8 ak1 = *(const bfx8*)&kb[akoff1];
        const float mb = (float)((mlo + i) * 64 + wave * 16 + g * 4);
        #pragma unroll
        for (int fn = 0; fn < 4; ++fn) {
            fx4 att = (fx4){0.f, 0.f, 0.f, 0.f};
            att = MFMA16(ak0, qf0[fn], att, 0, 0, 0);
            att = MFMA16(ak1, qf1[fn], att, 0, 0, 0);
            const float lgf = (float)(lt * 64 + fn * 16 + rl);
            float e0 = __expf(att[0] - 0.125f * fabsf(lgf - mb));
            float e1 = __expf(att[1] - 0.125f * fabsf(lgf - (mb + 1.f)));
            float e2 = __expf(att[2] - 0.125f * fabsf(lgf - (mb + 2.f)));
            float e3 = __expf(att[3] - 0.125f * fabsf(lgf - (mb + 3.f)));
            Sx[fn] += (e0 + e1) + (e2 + e3);
        }
    }
    #pragma unroll
    for (int fn = 0; fn < 4; ++fn) {
        float s_ = Sx[fn];
        s_ += __shfl_xor(s_, 16);
        s_ += __shfl_xor(s_, 32);
        if (lane < 16) sS[wave][fn * 16 + rl] = s_;
    }
    __syncthreads();
    if (t < 64) {
        float s_ = sS[0][t] + sS[1][t] + sS[2][t] + sS[3][t];
        rinv[(size_t)bh * L + lt * 64 + t] = 1.0f / s_;
    }
}

// ---------------------------------------------------------------------------
// Pass B (BANDED +-1 tile): O[d,m] = sum over l-tiles [mt-1, mt] of
// v[d,l]*w[l,m]; h = relu(O) -> hT[b][m][h*64+d]. grid (16, B*H).
// ---------------------------------------------------------------------------
__global__ __launch_bounds__(256) void attn_pv(
    const u16* __restrict__ qT, const u16* __restrict__ kT, const u16* __restrict__ v,
    const float* __restrict__ rinv, u16* __restrict__ hT)
{
    const int mt = blockIdx.x;
    const int bh = blockIdx.y;
    const int b = bh >> 5, h = bh & 31;
    const size_t qkbase = (size_t)b * L * AF + h * DH;
    const size_t vbase  = ((size_t)b * AF + h * DH) * L;
    const size_t rbase  = (size_t)bh * L;

    const int ltlo = mt < 1 ? 0 : mt - 1;
    const int NI = mt - ltlo + 1;    // 1..2
    const int m0 = mt * 64;

    __shared__ u16 lkt[64 * 64];
    __shared__ u16 lqt[2][64 * 64], lv[2][64 * 64];
    __shared__ u16 lw[64 * 68];   // wT[m][l], pad 68

    const int t = threadIdx.x, lane = t & 63, wave = t >> 6;
    const int rl = lane & 15, g = lane >> 4;

    const int s0 = t, s1 = t + 256;
    const int r0 = s0 >> 3, cs0 = (s0 & 7) ^ (r0 & 7);
    const int r1 = s1 >> 3, cs1 = (s1 & 7) ^ (r1 & 7);

    const u16* gq0 = qT + qkbase + (size_t)(ltlo * 64 + r0) * AF + cs0 * 8;
    const u16* gq1 = qT + qkbase + (size_t)(ltlo * 64 + r1) * AF + cs1 * 8;
    const u16* gv0 = v + vbase + ltlo * 64 + (size_t)r0 * L + cs0 * 8;
    const u16* gv1 = v + vbase + ltlo * 64 + (size_t)r1 * L + cs1 * 8;

    const int rmr = wave * 16 + rl;     // phase-1 A rows (m), phase-2 A rows (d)
    const int toff0 = rmr * 64 + ((g ^ (rmr & 7)) * 8);
    const int toff1 = rmr * 64 + (((g + 4) ^ (rmr & 7)) * 8);
    int qoff0[4], qoff1[4];
    #pragma unroll
    for (int f = 0; f < 4; ++f) {
        int rq = f * 16 + rl;
        qoff0[f] = rq * 64 + ((g ^ (rq & 7)) * 8);
        qoff1[f] = rq * 64 + (((g + 4) ^ (rq & 7)) * 8);
    }

    // prologue: K-tile + first q/v tile
    gld16(kT + qkbase + (size_t)(m0 + r0) * AF + cs0 * 8, lkt + s0 * 8);
    gld16(kT + qkbase + (size_t)(m0 + r1) * AF + cs1 * 8, lkt + s1 * 8);
    gld16(gq0, &lqt[0][s0 * 8]);
    gld16(gq1, &lqt[0][s1 * 8]);
    gld16(gv0, &lv[0][s0 * 8]);
    gld16(gv1, &lv[0][s1 * 8]);
    WAIT_VM(0); SBAR(); SFENCE();

    fx4 oa[4];
    #pragma unroll
    for (int f = 0; f < 4; ++f) oa[f] = (fx4){0.f, 0.f, 0.f, 0.f};

    int cur = 0;
    for (int i = 0; i < NI; ++i) {
        const int lt = ltlo + i;
        if (i + 1 < NI) {   // prefetch next q/v tile into the other buffer
            gld16(gq0 + (size_t)(i + 1) * 64 * AF, &lqt[cur ^ 1][s0 * 8]);
            gld16(gq1 + (size_t)(i + 1) * 64 * AF, &lqt[cur ^ 1][s1 * 8]);
            gld16(gv0 + (i + 1) * 64, &lv[cur ^ 1][s0 * 8]);
            gld16(gv1 + (i + 1) * 64, &lv[cur ^ 1][s1 * 8]);
        }
        // phase 1: att^T[m][l] = mfma(kT rows m, qT rows l) -> weights in lw
        bfx8 ak0 = *(const bfx8*)&lkt[toff0];
        bfx8 ak1 = *(const bfx8*)&lkt[toff1];
        const u16* qb = lqt[cur];
        #pragma unroll
        for (int fn = 0; fn < 4; ++fn) {
            bfx8 q0 = *(const bfx8*)&qb[qoff0[fn]];
            bfx8 q1 = *(const bfx8*)&qb[qoff1[fn]];
            fx4 att = (fx4){0.f, 0.f, 0.f, 0.f};
            att = MFMA16(ak0, q0, att, 0, 0, 0);
            att = MFMA16(ak1, q1, att, 0, 0, 0);
            const int lg = lt * 64 + fn * 16 + rl;
            float ri = rinv[rbase + lg];
            const float db = (float)(lg - (m0 + wave * 16 + g * 4));
            #pragma unroll
            for (int r = 0; r < 4; ++r) {
                int mloc = wave * 16 + g * 4 + r;
                float s = att[r] - 0.125f * fabsf(db - (float)r);
                float w = (lg <= m0 + mloc) ? __expf(s) * ri : 0.f;
                lw[mloc * 68 + fn * 16 + rl] = f2b(w);
            }
        }
        WAIT_LGKM0(); SBAR(); SFENCE();   // lw visible; prefetch stays in flight

        // phase 2: O[d][m] += mfma(v rows d, wT rows m)
        const u16* vb = lv[cur];
        bfx8 av0 = *(const bfx8*)&vb[toff0];
        bfx8 av1 = *(const bfx8*)&vb[toff1];
        #pragma unroll
        for (int fn = 0; fn < 4; ++fn) {
            const u16* wrow = &lw[(fn * 16 + rl) * 68];
            union { bfx8 f; bfx4 hh[2]; } w0, w1;
            w0.hh[0] = *(const bfx4*)&wrow[g * 8];
            w0.hh[1] = *(const bfx4*)&wrow[g * 8 + 4];
            w1.hh[0] = *(const bfx4*)&wrow[(g + 4) * 8];
            w1.hh[1] = *(const bfx4*)&wrow[(g + 4) * 8 + 4];
            oa[fn] = MFMA16(av0, w0.f, oa[fn], 0, 0, 0);
            oa[fn] = MFMA16(av1, w1.f, oa[fn], 0, 0, 0);
        }
        WAIT_VM(0); WAIT_LGKM0(); SBAR(); SFENCE();   // next tile landed; reads done
        cur ^= 1;
    }

    // epilogue: relu, C^T store -> hT[b][m][h*64+d]
    #pragma unroll
    for (int fn = 0; fn < 4; ++fn) {
        int mg = m0 + fn * 16 + rl;
        int cg = h * DH + wave * 16 + g * 4;
        us4 o = { f2b(fmaxf(oa[fn][0], 0.f)), f2b(fmaxf(oa[fn][1], 0.f)),
                  f2b(fmaxf(oa[fn][2], 0.f)), f2b(fmaxf(oa[fn][3], 0.f)) };
        *(us4*)(hT + ((size_t)b * L + mg) * AF + cg) = o;
    }
}

// ---------------------------------------------------------------------------
extern "C" void kernel_launch(void* const* d_in, const int* in_sizes, int n_in,
                              void* d_out, int out_size, void* d_ws, size_t ws_size,
                              hipStream_t stream)
{
    (void)in_sizes; (void)n_in; (void)out_size; (void)ws_size;
    const float* x  = (const float*)d_in[0];
    const float* Wq = (const float*)d_in[1];
    const float* bq = (const float*)d_in[2];
    const float* Wk = (const float*)d_in[3];
    const float* bk = (const float*)d_in[4];
    const float* Wv = (const float*)d_in[5];
    const float* bv = (const float*)d_in[6];
    const float* W1 = (const float*)d_in[7];
    const float* b1 = (const float*)d_in[8];
    const float* W2 = (const float*)d_in[9];
    const float* b2 = (const float*)d_in[10];

    u16* wsp = (u16*)d_ws;
    size_t o = 0;
    u16* xT  = wsp + o; o += (size_t)NB * L * CIN;
    u16* qT  = wsp + o; o += (size_t)NB * L * AF;   // q (pre-scaled by 1/8), [b][l][af]
    u16* kT  = wsp + o; o += (size_t)NB * L * AF;   // must follow qT (which*sWhich)
    u16* vdm = wsp + o; o += (size_t)NB * AF * L;   // v normal orientation [b][af][l]
    u16* hT  = wsp + o; o += (size_t)NB * L * AF;
    u16* z1T = wsp + o; o += (size_t)NB * L * AF;
    u16* Wqb = wsp + o; o += (size_t)AF * CIN;
    u16* Wkb = wsp + o; o += (size_t)AF * CIN;
    u16* Wvb = wsp + o; o += (size_t)AF * CIN;
    u16* W1b = wsp + o; o += (size_t)AF * AF;
    u16* W2b = wsp + o; o += (size_t)AF * AF;
    float* rinv = (float*)(wsp + o); o += (size_t)NB * NH * L * 2;

    dim3 blk(256);

    prep<<<dim3(512, 1, 6), blk, 0, stream>>>(x, Wq, Wk, Wv, W1, W2,
                                              xT, Wqb, Wkb, Wvb, W1b, W2b);

    // QKV: qT/kT = (W? * x)^T (q scaled 1/8); v -> vdm normal orientation
    gemm_bt<0, 1, 3, 3><<<dim3(16, 16, NB * 3), blk, 0, stream>>>(
        Wqb, Wkb, Wvb, bq, bk, bv, xT, qT, vdm,
        AF, L, CIN, (size_t)L * CIN, (size_t)L * AF, (size_t)NB * L * AF);

    attn_stats<<<dim3(16, NB * NH), blk, 0, stream>>>(qT, kT, rinv);
    attn_pv<<<dim3(16, NB * NH), blk, 0, stream>>>(qT, kT, vdm, rinv, hT);

    // z1T = relu(W1*h + b1)^T  -- BUFS=3 (BK=64; won R17 A/B)
    gemm_bt<1, 1, 1, 3><<<dim3(16, 16, NB), blk, 0, stream>>>(
        W1b, nullptr, nullptr, b1, nullptr, nullptr, hT, z1T, nullptr,
        AF, L, AF, (size_t)L * AF, (size_t)L * AF, 0);
    // out = W2*z1 + b2 (fp32) -- BUFS=3 rollout (same 2 blocks/CU as BUFS=6,
    // half the barriers; R15's 3-blocks/CU failure mode does not apply)
    gemm_bt<0, 0, 1, 3><<<dim3(16, 16, NB), blk, 0, stream>>>(
        W2b, nullptr, nullptr, b2, nullptr, nullptr, z1T, d_out, nullptr,
        AF, L, AF, (size_t)L * AF, (size_t)AF * L, 0);
}

// Round 19
// 127.412 us; speedup vs baseline: 1.1011x; 1.0308x over previous
//
#include <hip/hip_runtime.h>

#define L 1024
#define CIN 512
#define NH 32
#define DH 64
#define NB 2
#define AF 2048

typedef unsigned short u16;
typedef unsigned int u32;
typedef __attribute__((ext_vector_type(8))) short bfx8;   // 8 bf16 = 4 VGPR (MFMA A/B frag)
typedef __attribute__((ext_vector_type(4))) short bfx4;   // 8B half-frag
typedef __attribute__((ext_vector_type(4))) float fx4;    // MFMA C/D frag

struct __align__(8) us4 { u16 x, y, z, w; };

#define MFMA16 __builtin_amdgcn_mfma_f32_16x16x32_bf16
#define SBAR() __builtin_amdgcn_s_barrier()
#define SFENCE() __builtin_amdgcn_sched_barrier(0)
#define WAIT_VM(N) asm volatile("s_waitcnt vmcnt(" #N ")" ::: "memory")
#define WAIT_LGKM0() asm volatile("s_waitcnt lgkmcnt(0)" ::: "memory")

__device__ inline void gld16(const void* g, void* l) {
    __builtin_amdgcn_global_load_lds(
        (const __attribute__((address_space(1))) u32*)g,
        (__attribute__((address_space(3))) u32*)l, 16, 0, 0);
}

__device__ inline u16 f2b(float f) {
    union { float f; u32 u; } v; v.f = f;
    u32 u = v.u;
    return (u16)((u + 0x7fffu + ((u >> 16) & 1u)) >> 16);
}

// ---------------------------------------------------------------------------
// prep: all fp32->bf16 weight converts (z=0..4) + x transpose/convert (z=5).
// grid (512, 1, 6), block 256.
// ---------------------------------------------------------------------------
__global__ __launch_bounds__(256) void prep(
    const float* __restrict__ x,
    const float* __restrict__ Wq, const float* __restrict__ Wk, const float* __restrict__ Wv,
    const float* __restrict__ W1, const float* __restrict__ W2,
    u16* __restrict__ xT, u16* __restrict__ Wqb, u16* __restrict__ Wkb,
    u16* __restrict__ Wvb, u16* __restrict__ W1b, u16* __restrict__ W2b)
{
    __shared__ u16 tile[64][68];
    const int z = blockIdx.z;
    const int t = threadIdx.x;
    if (z < 5) {
        const float* in; u16* out; int n4;
        switch (z) {
            case 0: in = Wq; out = Wqb; n4 = AF * CIN / 4; break;
            case 1: in = Wk; out = Wkb; n4 = AF * CIN / 4; break;
            case 2: in = Wv; out = Wvb; n4 = AF * CIN / 4; break;
            case 3: in = W1; out = W1b; n4 = AF * AF / 4; break;
            default: in = W2; out = W2b; n4 = AF * AF / 4; break;
        }
        int i = blockIdx.x * 256 + t;
        for (; i < n4; i += 512 * 256) {
            float4 v = ((const float4*)in)[i];
            us4 o = { f2b(v.x), f2b(v.y), f2b(v.z), f2b(v.w) };
            ((us4*)out)[i] = o;
        }
    } else {
        const int bid = blockIdx.x;
        if (bid >= 256) return;
        const int c0 = (bid & 7) * 64, l0 = ((bid >> 3) & 15) * 64, b = bid >> 7;
        const int tr = t >> 4, tc4 = (t & 15) * 4;
        #pragma unroll
        for (int p = 0; p < 4; ++p) {
            int c = p * 16 + tr;
            float4 v = *(const float4*)(x + ((size_t)(b * CIN + c0 + c)) * L + l0 + tc4);
            tile[c][tc4 + 0] = f2b(v.x); tile[c][tc4 + 1] = f2b(v.y);
            tile[c][tc4 + 2] = f2b(v.z); tile[c][tc4 + 3] = f2b(v.w);
        }
        __syncthreads();
        #pragma unroll
        for (int p = 0; p < 4; ++p) {
            int l = p * 16 + tr;
            us4 o = { tile[tc4 + 0][l], tile[tc4 + 1][l], tile[tc4 + 2][l], tile[tc4 + 3][l] };
            *(us4*)(xT + ((size_t)(b * L + l0 + l)) * CIN + c0 + tc4) = o;
        }
    }
}

// ---------------------------------------------------------------------------
// MFMA GEMM, templated pipeline (BUFS selects schedule):
//  BUFS=3: BK=64, stage-after-barrier depth-2, 72 KB (2 blocks/CU).
//          Half the barrier pairs vs BK=32. Won R17/R18 (-7.2 us total).
//  BUFS=2: BK=64, stage-after-barrier depth-1, 48 KB (3 blocks/CU).
//          Combines the BK=64 cadence with R14's 3-blocks/CU TLP win.
//          Race-free: STAGE(it+1) targets buffer (it-1)&1 whose reads
//          retired before barrier(it); WAIT_VM(0) at loop top is minimal
//          (only tile-it's 6 loads in flight).
//  BUFS=6: BK=32, STAGE-before-waits depth-3, 72 KB (legacy fallback).
//  BUFS=4: BK=32, stage-after-barrier depth-3, 48 KB.
// C[M,N] = A[M,K] * B[K,N] (+bias[M], opt relu). A row-major, BT=[N][K].
// Tile 128(M) x 64(N), 256 threads = 4 waves (2x2, wave-tile 64x32).
// Grid is ALWAYS (16,16,z): requires M=2048, N=1024. XCD-contiguous remap.
// CT_OUT=1: store C^T bf16 [N][M].  CT_OUT=0: store C fp32 [M][N].
// NA=3 (QKV): grid.z = b*3+which; which==0 scales output by 0.125 (q/sqrt(D));
//             which==2 stores NORMAL orientation bf16 [b][M][N] into Cb2.
// ---------------------------------------------------------------------------
template<int RELU, int CT_OUT, int NA, int BUFS>
__global__ __launch_bounds__(256) void gemm_bt(
    const u16* __restrict__ A0, const u16* __restrict__ A1, const u16* __restrict__ A2,
    const float* __restrict__ bias0, const float* __restrict__ bias1, const float* __restrict__ bias2,
    const u16* __restrict__ BTb, void* __restrict__ Cb, void* __restrict__ Cb2,
    int M, int N, int K, size_t sBT, size_t sC, size_t sWhich)
{
    const int z = blockIdx.z;
    const int which = (NA == 3) ? (z % 3) : 0;
    const int b     = (NA == 3) ? (z / 3) : z;
    const u16* __restrict__ A = (which == 0) ? A0 : (which == 1) ? A1 : A2;
    const float* __restrict__ bias = (which == 0) ? bias0 : (which == 1) ? bias1 : bias2;
    const u16* __restrict__ BT = BTb + (size_t)b * sBT;

    // XCD-contiguous tile remap: XCD k (= lin%8) owns 2 N-columns x all 16 M-tiles
    const int lin  = blockIdx.x + (blockIdx.y << 4);
    const int lin2 = ((lin & 7) << 5) + (lin >> 3);
    const int n0 = (lin2 >> 4) * 64;
    const int m0 = (lin2 & 15) * 128;

    constexpr int BKv = (BUFS <= 3) ? 64 : 32;
    __shared__ u16 lA[BUFS * 128 * BKv];
    __shared__ u16 lB[BUFS * 64 * BKv];

    const int t = threadIdx.x, lane = t & 63, wave = t >> 6;
    const int wm = (wave >> 1) * 64, wn = (wave & 1) * 32;
    const int rl = lane & 15, kh = lane >> 4;

    fx4 acc[4][2];
    #pragma unroll
    for (int i = 0; i < 4; ++i)
        #pragma unroll
        for (int j = 0; j < 2; ++j) acc[i][j] = (fx4){0.f, 0.f, 0.f, 0.f};

    const int NT = K / BKv;

    if (BUFS <= 3) {
        // ===== BK=64 paths =====
        // staging: A 1024 16B-slots (4/thread), B 512 slots (2/thread).
        // slot s -> row s>>3, chunk-pos s&7; src chunk = pos ^ (row&7)
        const u16* gAp[4]; int dA[4];
        #pragma unroll
        for (int i = 0; i < 4; ++i) {
            int s = t + i * 256, row = s >> 3, src = (s & 7) ^ (row & 7);
            dA[i] = s * 8;
            gAp[i] = A + (size_t)(m0 + row) * K + src * 8;
        }
        const u16* gBp[2]; int dB[2];
        #pragma unroll
        for (int i = 0; i < 2; ++i) {
            int s = t + i * 256, row = s >> 3, src = (s & 7) ^ (row & 7);
            dB[i] = s * 8;
            gBp[i] = BT + (size_t)(n0 + row) * K + src * 8;
        }
        // frag offsets: half h, k-chunk c = h*4+kh; row r -> r*64 + ((c^(r&7))*8)
        int aoff[2][4], boff[2][2];
        #pragma unroll
        for (int h = 0; h < 2; ++h) {
            #pragma unroll
            for (int f = 0; f < 4; ++f) {
                int ra = wm + f * 16 + rl;
                aoff[h][f] = ra * 64 + (((h * 4 + kh) ^ (ra & 7)) * 8);
            }
            #pragma unroll
            for (int f = 0; f < 2; ++f) {
                int rb = wn + f * 16 + rl;
                boff[h][f] = rb * 64 + (((h * 4 + kh) ^ (rb & 7)) * 8);
            }
        }
#define STAGE64(BF, K0) do { \
        gld16(gAp[0] + (K0), &lA[(BF) * 128 * 64 + dA[0]]); \
        gld16(gAp[1] + (K0), &lA[(BF) * 128 * 64 + dA[1]]); \
        gld16(gAp[2] + (K0), &lA[(BF) * 128 * 64 + dA[2]]); \
        gld16(gAp[3] + (K0), &lA[(BF) * 128 * 64 + dA[3]]); \
        gld16(gBp[0] + (K0), &lB[(BF) * 64 * 64 + dB[0]]); \
        gld16(gBp[1] + (K0), &lB[(BF) * 64 * 64 + dB[1]]); } while (0)

#define COMPUTE64(BF) do { \
        const u16* bA_ = &lA[(BF) * 128 * 64]; \
        const u16* bB_ = &lB[(BF) * 64 * 64]; \
        __builtin_amdgcn_s_setprio(1); \
        _Pragma("unroll") \
        for (int h = 0; h < 2; ++h) { \
            bfx8 af[4], bfr[2]; \
            af[0] = *(const bfx8*)&bA_[aoff[h][0]]; \
            af[1] = *(const bfx8*)&bA_[aoff[h][1]]; \
            af[2] = *(const bfx8*)&bA_[aoff[h][2]]; \
            af[3] = *(const bfx8*)&bA_[aoff[h][3]]; \
            bfr[0] = *(const bfx8*)&bB_[boff[h][0]]; \
            bfr[1] = *(const bfx8*)&bB_[boff[h][1]]; \
            _Pragma("unroll") \
            for (int fm = 0; fm < 4; ++fm) \
                _Pragma("unroll") \
                for (int fn = 0; fn < 2; ++fn) \
                    acc[fm][fn] = MFMA16(af[fm], bfr[fn], acc[fm][fn], 0, 0, 0); \
        } \
        __builtin_amdgcn_s_setprio(0); } while (0)

        if (BUFS == 3) {
            STAGE64(0, 0); STAGE64(1, 64);
            int bcur = 0, bst = 2;
            for (int it = 0; it < NT; ++it) {
                if (it + 1 < NT) { WAIT_VM(6); } else { WAIT_VM(0); }
                SBAR(); SFENCE();
                if (it + 2 < NT) STAGE64(bst, (it + 2) << 6);
                COMPUTE64(bcur);
                if (++bcur == 3) bcur = 0;
                if (++bst == 3) bst = 0;
            }
        } else {
            // BUFS=2: depth-1, 48 KB -> 3 blocks/CU
            STAGE64(0, 0);
            for (int it = 0; it < NT; ++it) {
                WAIT_VM(0);            // only tile-it's 6 loads in flight
                SBAR(); SFENCE();
                if (it + 1 < NT) STAGE64((it + 1) & 1, (it + 1) << 6);
                COMPUTE64(it & 1);
            }
        }
#undef STAGE64
#undef COMPUTE64
    } else {
        // ===== BK=32 paths (legacy) =====
        const int sA0 = t, sA1 = t + 256, sB = t;
        const int rA0 = sA0 >> 2, cA0 = (sA0 & 3) ^ ((rA0 >> 1) & 3);
        const int rA1 = sA1 >> 2, cA1 = (sA1 & 3) ^ ((rA1 >> 1) & 3);
        const int rB  = sB  >> 2, cB  = (sB  & 3) ^ ((rB  >> 1) & 3);
        const u16* gA0 = A  + (size_t)(m0 + rA0) * K + cA0 * 8;
        const u16* gA1 = A  + (size_t)(m0 + rA1) * K + cA1 * 8;
        const u16* gB0 = BT + (size_t)(n0 + rB) * K + cB * 8;

        int aoff[4], boff[2];
        #pragma unroll
        for (int f = 0; f < 4; ++f) {
            int ra = wm + f * 16 + rl;
            aoff[f] = ra * 32 + ((kh ^ ((ra >> 1) & 3)) * 8);
        }
        #pragma unroll
        for (int f = 0; f < 2; ++f) {
            int rb = wn + f * 16 + rl;
            boff[f] = rb * 32 + ((kh ^ ((rb >> 1) & 3)) * 8);
        }

#define STAGE32(BF, K0) do { \
        gld16(gA0 + (K0), &lA[(BF) * 128 * 32 + sA0 * 8]); \
        gld16(gA1 + (K0), &lA[(BF) * 128 * 32 + sA1 * 8]); \
        gld16(gB0 + (K0), &lB[(BF) * 64 * 32 + sB * 8]); } while (0)

#define COMPUTE32(BF) do { \
        const u16* bA_ = &lA[(BF) * 128 * 32]; \
        const u16* bB_ = &lB[(BF) * 64 * 32]; \
        bfx8 af[4], bfr[2]; \
        af[0] = *(const bfx8*)&bA_[aoff[0]]; \
        af[1] = *(const bfx8*)&bA_[aoff[1]]; \
        af[2] = *(const bfx8*)&bA_[aoff[2]]; \
        af[3] = *(const bfx8*)&bA_[aoff[3]]; \
        bfr[0] = *(const bfx8*)&bB_[boff[0]]; \
        bfr[1] = *(const bfx8*)&bB_[boff[1]]; \
        __builtin_amdgcn_s_setprio(1); \
        _Pragma("unroll") \
        for (int fm = 0; fm < 4; ++fm) \
            _Pragma("unroll") \
            for (int fn = 0; fn < 2; ++fn) \
                acc[fm][fn] = MFMA16(af[fm], bfr[fn], acc[fm][fn], 0, 0, 0); \
        __builtin_amdgcn_s_setprio(0); } while (0)

        if (BUFS == 6) {
            STAGE32(0, 0); STAGE32(1, 32); STAGE32(2, 64);
            WAIT_VM(6); SBAR(); SFENCE();
            int bcur = 0, bpre = 3;
            for (int it = 0; it < NT; ++it) {
                if (it + 3 < NT) {
                    STAGE32(bpre, (it + 3) << 5);
                    WAIT_VM(9);
                } else if (it + 2 < NT) {
                    WAIT_VM(6);
                } else if (it + 1 < NT) {
                    WAIT_VM(3);
                } else {
                    WAIT_VM(0);
                }
                SBAR(); SFENCE();
                COMPUTE32(bcur);
                if (++bcur == 6) bcur = 0;
                if (++bpre == 6) bpre = 0;
            }
        } else {
            STAGE32(0, 0); STAGE32(1, 32); STAGE32(2, 64);
            for (int it = 0; it < NT; ++it) {
                const int rem = NT - 1 - it;
                if (rem >= 2) { WAIT_VM(6); }
                else if (rem == 1) { WAIT_VM(3); }
                else { WAIT_VM(0); }
                SBAR(); SFENCE();
                if (it + 3 < NT) STAGE32((it + 3) & 3, (it + 3) << 5);
                COMPUTE32(it & 3);
            }
        }
#undef STAGE32
#undef COMPUTE32
    }

    if (NA == 3 && which == 2) {
        // v: store normal orientation bf16 [b][M][N]
        u16* Vn = (u16*)Cb2 + (size_t)b * (size_t)M * N;
        #pragma unroll
        for (int fm = 0; fm < 4; ++fm) {
            int mg = m0 + wm + fm * 16 + kh * 4;
            #pragma unroll
            for (int fn = 0; fn < 2; ++fn) {
                int ng = n0 + wn + fn * 16 + rl;
                #pragma unroll
                for (int r = 0; r < 4; ++r)
                    Vn[(size_t)(mg + r) * N + ng] = f2b(acc[fm][fn][r] + bias[mg + r]);
            }
        }
    } else if (CT_OUT) {
        const float sc = (NA == 3 && which == 0) ? 0.125f : 1.0f;
        u16* CT = (u16*)Cb + (size_t)which * sWhich + (size_t)b * sC;
        #pragma unroll
        for (int fm = 0; fm < 4; ++fm) {
            int mg = m0 + wm + fm * 16 + kh * 4;
            float bi0 = bias[mg], bi1 = bias[mg + 1], bi2 = bias[mg + 2], bi3 = bias[mg + 3];
            #pragma unroll
            for (int fn = 0; fn < 2; ++fn) {
                int ng = n0 + wn + fn * 16 + rl;
                float v0 = (acc[fm][fn][0] + bi0) * sc;
                float v1 = (acc[fm][fn][1] + bi1) * sc;
                float v2 = (acc[fm][fn][2] + bi2) * sc;
                float v3 = (acc[fm][fn][3] + bi3) * sc;
                if (RELU) {
                    v0 = fmaxf(v0, 0.f); v1 = fmaxf(v1, 0.f);
                    v2 = fmaxf(v2, 0.f); v3 = fmaxf(v3, 0.f);
                }
                us4 o = { f2b(v0), f2b(v1), f2b(v2), f2b(v3) };
                *(us4*)(CT + (size_t)ng * M + mg) = o;
            }
        }
    } else {
        float* C = (float*)Cb + (size_t)b * sC;
        #pragma unroll
        for (int fm = 0; fm < 4; ++fm) {
            int mg = m0 + wm + fm * 16 + kh * 4;
            #pragma unroll
            for (int fn = 0; fn < 2; ++fn) {
                int ng = n0 + wn + fn * 16 + rl;
                #pragma unroll
                for (int r = 0; r < 4; ++r) {
                    float v = acc[fm][fn][r] + bias[mg + r];
                    if (RELU) v = fmaxf(v, 0.f);
                    C[(size_t)(mg + r) * N + ng] = v;
                }
            }
        }
    }
}

// ---------------------------------------------------------------------------
// Pass A (BANDED +-1 tile, W=64): S[l] = sum_{m in tiles [lt-1,lt+1]}
// exp(att[l,m] - |l-m|/8). Verified numerically free in R12/R13.
// Block = 64 l-rows of one (b,h). grid (16, B*H). Depth-2 prefetch.
// ---------------------------------------------------------------------------
__global__ __launch_bounds__(256) void attn_stats(
    const u16* __restrict__ qT, const u16* __restrict__ kT,
    float* __restrict__ rinv)
{
    const int lt = blockIdx.x;
    const int bh = blockIdx.y;
    const int b = bh >> 5, h = bh & 31;
    const size_t base = (size_t)b * L * AF + h * DH;

    const int mlo = lt < 1 ? 0 : lt - 1;
    const int mhi = lt > 14 ? 15 : lt + 1;
    const int NTW = mhi - mlo + 1;   // 2..3 always

    __shared__ u16 lq[64 * 64];
    __shared__ u16 lk[4][64 * 64];
    __shared__ float sS[4][64];

    const int t = threadIdx.x, lane = t & 63, wave = t >> 6;
    const int rl = lane & 15, g = lane >> 4;

    const int s0 = t, s1 = t + 256;
    const int r0 = s0 >> 3, cs0 = (s0 & 7) ^ (r0 & 7);
    const int r1 = s1 >> 3, cs1 = (s1 & 7) ^ (r1 & 7);

    const u16* gk0 = kT + base + (size_t)(mlo * 64 + r0) * AF + cs0 * 8;
    const u16* gk1 = kT + base + (size_t)(mlo * 64 + r1) * AF + cs1 * 8;

    gld16(qT + base + (size_t)(lt * 64 + r0) * AF + cs0 * 8, lq + s0 * 8);
    gld16(qT + base + (size_t)(lt * 64 + r1) * AF + cs1 * 8, lq + s1 * 8);
    gld16(gk0, &lk[0][s0 * 8]);
    gld16(gk1, &lk[0][s1 * 8]);
    gld16(gk0 + (size_t)64 * AF, &lk[1][s0 * 8]);
    gld16(gk1 + (size_t)64 * AF, &lk[1][s1 * 8]);
    WAIT_VM(2); SBAR(); SFENCE();    // q + k0 landed

    const int rmr = wave * 16 + rl;
    const int akoff0 = rmr * 64 + ((g ^ (rmr & 7)) * 8);
    const int akoff1 = rmr * 64 + (((g + 4) ^ (rmr & 7)) * 8);
    bfx8 qf0[4], qf1[4];
    #pragma unroll
    for (int f = 0; f < 4; ++f) {
        int rq = f * 16 + rl;
        qf0[f] = *(const bfx8*)&lq[rq * 64 + ((g ^ (rq & 7)) * 8)];
        qf1[f] = *(const bfx8*)&lq[rq * 64 + (((g + 4) ^ (rq & 7)) * 8)];
    }

    float Sx[4] = {0.f, 0.f, 0.f, 0.f};
    for (int i = 0; i < NTW; ++i) {
        if (i + 2 < NTW) {
            const int bf = (i + 2) & 3;
            gld16(gk0 + (size_t)(i + 2) * 64 * AF, &lk[bf][s0 * 8]);
            gld16(gk1 + (size_t)(i + 2) * 64 * AF, &lk[bf][s1 * 8]);
            WAIT_VM(4);
        } else if (i + 1 < NTW) {
            WAIT_VM(2);
        } else {
            WAIT_VM(0);
        }
        SBAR(); SFENCE();
        const u16* kb = lk[i & 3];
        bfx8 ak0 = *(const bfx8*)&kb[akoff0];
        bfx8 ak1 = *(const bfx8*)&kb[akoff1];
        const float mb = (float)((mlo + i) * 64 + wave * 16 + g * 4);
        #pragma unroll
        for (int fn = 0; fn < 4; ++fn) {
            fx4 att = (fx4){0.f, 0.f, 0.f, 0.f};
            att = MFMA16(ak0, qf0[fn], att, 0, 0, 0);
            att = MFMA16(ak1, qf1[fn], att, 0, 0, 0);
            const float lgf = (float)(lt * 64 + fn * 16 + rl);
            float e0 = __expf(att[0] - 0.125f * fabsf(lgf - mb));
            float e1 = __expf(att[1] - 0.125f * fabsf(lgf - (mb + 1.f)));
            float e2 = __expf(att[2] - 0.125f * fabsf(lgf - (mb + 2.f)));
            float e3 = __expf(att[3] - 0.125f * fabsf(lgf - (mb + 3.f)));
            Sx[fn] += (e0 + e1) + (e2 + e3);
        }
    }
    #pragma unroll
    for (int fn = 0; fn < 4; ++fn) {
        float s_ = Sx[fn];
        s_ += __shfl_xor(s_, 16);
        s_ += __shfl_xor(s_, 32);
        if (lane < 16) sS[wave][fn * 16 + rl] = s_;
    }
    __syncthreads();
    if (t < 64) {
        float s_ = sS[0][t] + sS[1][t] + sS[2][t] + sS[3][t];
        rinv[(size_t)bh * L + lt * 64 + t] = 1.0f / s_;
    }
}

// ---------------------------------------------------------------------------
// Pass B (BANDED +-1 tile): O[d,m] = sum over l-tiles [mt-1, mt] of
// v[d,l]*w[l,m]; h = relu(O) -> hT[b][m][h*64+d]. grid (16, B*H).
// ---------------------------------------------------------------------------
__global__ __launch_bounds__(256) void attn_pv(
    const u16* __restrict__ qT, const u16* __restrict__ kT, const u16* __restrict__ v,
    const float* __restrict__ rinv, u16* __restrict__ hT)
{
    const int mt = blockIdx.x;
    const int bh = blockIdx.y;
    const int b = bh >> 5, h = bh & 31;
    const size_t qkbase = (size_t)b * L * AF + h * DH;
    const size_t vbase  = ((size_t)b * AF + h * DH) * L;
    const size_t rbase  = (size_t)bh * L;

    const int ltlo = mt < 1 ? 0 : mt - 1;
    const int NI = mt - ltlo + 1;    // 1..2
    const int m0 = mt * 64;

    __shared__ u16 lkt[64 * 64];
    __shared__ u16 lqt[2][64 * 64], lv[2][64 * 64];
    __shared__ u16 lw[64 * 68];   // wT[m][l], pad 68

    const int t = threadIdx.x, lane = t & 63, wave = t >> 6;
    const int rl = lane & 15, g = lane >> 4;

    const int s0 = t, s1 = t + 256;
    const int r0 = s0 >> 3, cs0 = (s0 & 7) ^ (r0 & 7);
    const int r1 = s1 >> 3, cs1 = (s1 & 7) ^ (r1 & 7);

    const u16* gq0 = qT + qkbase + (size_t)(ltlo * 64 + r0) * AF + cs0 * 8;
    const u16* gq1 = qT + qkbase + (size_t)(ltlo * 64 + r1) * AF + cs1 * 8;
    const u16* gv0 = v + vbase + ltlo * 64 + (size_t)r0 * L + cs0 * 8;
    const u16* gv1 = v + vbase + ltlo * 64 + (size_t)r1 * L + cs1 * 8;

    const int rmr = wave * 16 + rl;     // phase-1 A rows (m), phase-2 A rows (d)
    const int toff0 = rmr * 64 + ((g ^ (rmr & 7)) * 8);
    const int toff1 = rmr * 64 + (((g + 4) ^ (rmr & 7)) * 8);
    int qoff0[4], qoff1[4];
    #pragma unroll
    for (int f = 0; f < 4; ++f) {
        int rq = f * 16 + rl;
        qoff0[f] = rq * 64 + ((g ^ (rq & 7)) * 8);
        qoff1[f] = rq * 64 + (((g + 4) ^ (rq & 7)) * 8);
    }

    // prologue: K-tile + first q/v tile
    gld16(kT + qkbase + (size_t)(m0 + r0) * AF + cs0 * 8, lkt + s0 * 8);
    gld16(kT + qkbase + (size_t)(m0 + r1) * AF + cs1 * 8, lkt + s1 * 8);
    gld16(gq0, &lqt[0][s0 * 8]);
    gld16(gq1, &lqt[0][s1 * 8]);
    gld16(gv0, &lv[0][s0 * 8]);
    gld16(gv1, &lv[0][s1 * 8]);
    WAIT_VM(0); SBAR(); SFENCE();

    fx4 oa[4];
    #pragma unroll
    for (int f = 0; f < 4; ++f) oa[f] = (fx4){0.f, 0.f, 0.f, 0.f};

    int cur = 0;
    for (int i = 0; i < NI; ++i) {
        const int lt = ltlo + i;
        if (i + 1 < NI) {   // prefetch next q/v tile into the other buffer
            gld16(gq0 + (size_t)(i + 1) * 64 * AF, &lqt[cur ^ 1][s0 * 8]);
            gld16(gq1 + (size_t)(i + 1) * 64 * AF, &lqt[cur ^ 1][s1 * 8]);
            gld16(gv0 + (i + 1) * 64, &lv[cur ^ 1][s0 * 8]);
            gld16(gv1 + (i + 1) * 64, &lv[cur ^ 1][s1 * 8]);
        }
        // phase 1: att^T[m][l] = mfma(kT rows m, qT rows l) -> weights in lw
        bfx8 ak0 = *(const bfx8*)&lkt[toff0];
        bfx8 ak1 = *(const bfx8*)&lkt[toff1];
        const u16* qb = lqt[cur];
        #pragma unroll
        for (int fn = 0; fn < 4; ++fn) {
            bfx8 q0 = *(const bfx8*)&qb[qoff0[fn]];
            bfx8 q1 = *(const bfx8*)&qb[qoff1[fn]];
            fx4 att = (fx4){0.f, 0.f, 0.f, 0.f};
            att = MFMA16(ak0, q0, att, 0, 0, 0);
            att = MFMA16(ak1, q1, att, 0, 0, 0);
            const int lg = lt * 64 + fn * 16 + rl;
            float ri = rinv[rbase + lg];
            const float db = (float)(lg - (m0 + wave * 16 + g * 4));
            #pragma unroll
            for (int r = 0; r < 4; ++r) {
                int mloc = wave * 16 + g * 4 + r;
                float s = att[r] - 0.125f * fabsf(db - (float)r);
                float w = (lg <= m0 + mloc) ? __expf(s) * ri : 0.f;
                lw[mloc * 68 + fn * 16 + rl] = f2b(w);
            }
        }
        WAIT_LGKM0(); SBAR(); SFENCE();   // lw visible; prefetch stays in flight

        // phase 2: O[d][m] += mfma(v rows d, wT rows m)
        const u16* vb = lv[cur];
        bfx8 av0 = *(const bfx8*)&vb[toff0];
        bfx8 av1 = *(const bfx8*)&vb[toff1];
        #pragma unroll
        for (int fn = 0; fn < 4; ++fn) {
            const u16* wrow = &lw[(fn * 16 + rl) * 68];
            union { bfx8 f; bfx4 hh[2]; } w0, w1;
            w0.hh[0] = *(const bfx4*)&wrow[g * 8];
            w0.hh[1] = *(const bfx4*)&wrow[g * 8 + 4];
            w1.hh[0] = *(const bfx4*)&wrow[(g + 4) * 8];
            w1.hh[1] = *(const bfx4*)&wrow[(g + 4) * 8 + 4];
            oa[fn] = MFMA16(av0, w0.f, oa[fn], 0, 0, 0);
            oa[fn] = MFMA16(av1, w1.f, oa[fn], 0, 0, 0);
        }
        WAIT_VM(0); WAIT_LGKM0(); SBAR(); SFENCE();   // next tile landed; reads done
        cur ^= 1;
    }

    // epilogue: relu, C^T store -> hT[b][m][h*64+d]
    #pragma unroll
    for (int fn = 0; fn < 4; ++fn) {
        int mg = m0 + fn * 16 + rl;
        int cg = h * DH + wave * 16 + g * 4;
        us4 o = { f2b(fmaxf(oa[fn][0], 0.f)), f2b(fmaxf(oa[fn][1], 0.f)),
                  f2b(fmaxf(oa[fn][2], 0.f)), f2b(fmaxf(oa[fn][3], 0.f)) };
        *(us4*)(hT + ((size_t)b * L + mg) * AF + cg) = o;
    }
}

// ---------------------------------------------------------------------------
extern "C" void kernel_launch(void* const* d_in, const int* in_sizes, int n_in,
                              void* d_out, int out_size, void* d_ws, size_t ws_size,
                              hipStream_t stream)
{
    (void)in_sizes; (void)n_in; (void)out_size; (void)ws_size;
    const float* x  = (const float*)d_in[0];
    const float* Wq = (const float*)d_in[1];
    const float* bq = (const float*)d_in[2];
    const float* Wk = (const float*)d_in[3];
    const float* bk = (const float*)d_in[4];
    const float* Wv = (const float*)d_in[5];
    const float* bv = (const float*)d_in[6];
    const float* W1 = (const float*)d_in[7];
    const float* b1 = (const float*)d_in[8];
    const float* W2 = (const float*)d_in[9];
    const float* b2 = (const float*)d_in[10];

    u16* wsp = (u16*)d_ws;
    size_t o = 0;
    u16* xT  = wsp + o; o += (size_t)NB * L * CIN;
    u16* qT  = wsp + o; o += (size_t)NB * L * AF;   // q (pre-scaled by 1/8), [b][l][af]
    u16* kT  = wsp + o; o += (size_t)NB * L * AF;   // must follow qT (which*sWhich)
    u16* vdm = wsp + o; o += (size_t)NB * AF * L;   // v normal orientation [b][af][l]
    u16* hT  = wsp + o; o += (size_t)NB * L * AF;
    u16* z1T = wsp + o; o += (size_t)NB * L * AF;
    u16* Wqb = wsp + o; o += (size_t)AF * CIN;
    u16* Wkb = wsp + o; o += (size_t)AF * CIN;
    u16* Wvb = wsp + o; o += (size_t)AF * CIN;
    u16* W1b = wsp + o; o += (size_t)AF * AF;
    u16* W2b = wsp + o; o += (size_t)AF * AF;
    float* rinv = (float*)(wsp + o); o += (size_t)NB * NH * L * 2;

    dim3 blk(256);

    prep<<<dim3(512, 1, 6), blk, 0, stream>>>(x, Wq, Wk, Wv, W1, W2,
                                              xT, Wqb, Wkb, Wvb, W1b, W2b);

    // QKV: qT/kT = (W? * x)^T (q scaled 1/8); v -> vdm normal orientation
    // BUFS=2 (BK=64, 48 KB, 3 blocks/CU) -- A-arm
    gemm_bt<0, 1, 3, 2><<<dim3(16, 16, NB * 3), blk, 0, stream>>>(
        Wqb, Wkb, Wvb, bq, bk, bv, xT, qT, vdm,
        AF, L, CIN, (size_t)L * CIN, (size_t)L * AF, (size_t)NB * L * AF);

    attn_stats<<<dim3(16, NB * NH), blk, 0, stream>>>(qT, kT, rinv);
    attn_pv<<<dim3(16, NB * NH), blk, 0, stream>>>(qT, kT, vdm, rinv, hT);

    // z1T = relu(W1*h + b1)^T  -- BUFS=2 (BK=64, 3 blocks/CU) A-arm
    gemm_bt<1, 1, 1, 2><<<dim3(16, 16, NB), blk, 0, stream>>>(
        W1b, nullptr, nullptr, b1, nullptr, nullptr, hT, z1T, nullptr,
        AF, L, AF, (size_t)L * AF, (size_t)L * AF, 0);
    // out = W2*z1 + b2 (fp32) -- BUFS=3 CONTROL (R18 winner)
    gemm_bt<0, 0, 1, 3><<<dim3(16, 16, NB), blk, 0, stream>>>(
        W2b, nullptr, nullptr, b2, nullptr, nullptr, z1T, d_out, nullptr,
        AF, L, AF, (size_t)L * AF, (size_t)AF * L, 0);
}

// Round 20
// 127.104 us; speedup vs baseline: 1.1037x; 1.0024x over previous
//
#include <hip/hip_runtime.h>

#define L 1024
#define CIN 512
#define NH 32
#define DH 64
#define NB 2
#define AF 2048

typedef unsigned short u16;
typedef unsigned int u32;
typedef __attribute__((ext_vector_type(8))) short bfx8;   // 8 bf16 = 4 VGPR (MFMA A/B frag)
typedef __attribute__((ext_vector_type(4))) short bfx4;   // 8B half-frag
typedef __attribute__((ext_vector_type(4))) float fx4;    // MFMA C/D frag

struct __align__(8) us4 { u16 x, y, z, w; };

#define MFMA16 __builtin_amdgcn_mfma_f32_16x16x32_bf16
#define SBAR() __builtin_amdgcn_s_barrier()
#define SFENCE() __builtin_amdgcn_sched_barrier(0)
#define WAIT_VM(N) asm volatile("s_waitcnt vmcnt(" #N ")" ::: "memory")
#define WAIT_LGKM0() asm volatile("s_waitcnt lgkmcnt(0)" ::: "memory")

__device__ inline void gld16(const void* g, void* l) {
    __builtin_amdgcn_global_load_lds(
        (const __attribute__((address_space(1))) u32*)g,
        (__attribute__((address_space(3))) u32*)l, 16, 0, 0);
}

__device__ inline u16 f2b(float f) {
    union { float f; u32 u; } v; v.f = f;
    u32 u = v.u;
    return (u16)((u + 0x7fffu + ((u >> 16) & 1u)) >> 16);
}

// ---------------------------------------------------------------------------
// prep: all fp32->bf16 weight converts (z=0..4) + x transpose/convert (z=5).
// grid (512, 1, 6), block 256.
// ---------------------------------------------------------------------------
__global__ __launch_bounds__(256) void prep(
    const float* __restrict__ x,
    const float* __restrict__ Wq, const float* __restrict__ Wk, const float* __restrict__ Wv,
    const float* __restrict__ W1, const float* __restrict__ W2,
    u16* __restrict__ xT, u16* __restrict__ Wqb, u16* __restrict__ Wkb,
    u16* __restrict__ Wvb, u16* __restrict__ W1b, u16* __restrict__ W2b)
{
    __shared__ u16 tile[64][68];
    const int z = blockIdx.z;
    const int t = threadIdx.x;
    if (z < 5) {
        const float* in; u16* out; int n4;
        switch (z) {
            case 0: in = Wq; out = Wqb; n4 = AF * CIN / 4; break;
            case 1: in = Wk; out = Wkb; n4 = AF * CIN / 4; break;
            case 2: in = Wv; out = Wvb; n4 = AF * CIN / 4; break;
            case 3: in = W1; out = W1b; n4 = AF * AF / 4; break;
            default: in = W2; out = W2b; n4 = AF * AF / 4; break;
        }
        int i = blockIdx.x * 256 + t;
        for (; i < n4; i += 512 * 256) {
            float4 v = ((const float4*)in)[i];
            us4 o = { f2b(v.x), f2b(v.y), f2b(v.z), f2b(v.w) };
            ((us4*)out)[i] = o;
        }
    } else {
        const int bid = blockIdx.x;
        if (bid >= 256) return;
        const int c0 = (bid & 7) * 64, l0 = ((bid >> 3) & 15) * 64, b = bid >> 7;
        const int tr = t >> 4, tc4 = (t & 15) * 4;
        #pragma unroll
        for (int p = 0; p < 4; ++p) {
            int c = p * 16 + tr;
            float4 v = *(const float4*)(x + ((size_t)(b * CIN + c0 + c)) * L + l0 + tc4);
            tile[c][tc4 + 0] = f2b(v.x); tile[c][tc4 + 1] = f2b(v.y);
            tile[c][tc4 + 2] = f2b(v.z); tile[c][tc4 + 3] = f2b(v.w);
        }
        __syncthreads();
        #pragma unroll
        for (int p = 0; p < 4; ++p) {
            int l = p * 16 + tr;
            us4 o = { tile[tc4 + 0][l], tile[tc4 + 1][l], tile[tc4 + 2][l], tile[tc4 + 3][l] };
            *(us4*)(xT + ((size_t)(b * L + l0 + l)) * CIN + c0 + tc4) = o;
        }
    }
}

// ---------------------------------------------------------------------------
// MFMA GEMM, templated pipeline (BUFS selects schedule):
//  BUFS=2: BK=64, stage-after-barrier depth-1, 48 KB (3 blocks/CU).
//          BK=64 cadence + 3-blocks/CU TLP. Won R19 (-3.9 us on QKV+W1).
//          Race-free: STAGE(it+1) targets buffer (it-1)&1 whose reads
//          retired before barrier(it).
//  BUFS=3: BK=64, stage-after-barrier depth-2, 72 KB (2 blocks/CU).
//          Won R17/R18 (-7.2 us).
//  BUFS=6/4: BK=32 legacy schedules.
// C[M,N] = A[M,K] * B[K,N] (+bias[M], opt relu). A row-major, BT=[N][K].
// Tile 128(M) x 64(N), 256 threads = 4 waves (2x2, wave-tile 64x32).
// Grid is ALWAYS (16,16,z): requires M=2048, N=1024. XCD-contiguous remap.
// CT_OUT=1: store C^T bf16 [N][M].  CT_OUT=0: store C fp32 [M][N].
// NA=3 (QKV): grid.z = b*3+which; which==0 scales output by 0.125 (q/sqrt(D));
//             which==2 stores NORMAL orientation bf16 [b][M][N] into Cb2.
// ---------------------------------------------------------------------------
template<int RELU, int CT_OUT, int NA, int BUFS>
__global__ __launch_bounds__(256) void gemm_bt(
    const u16* __restrict__ A0, const u16* __restrict__ A1, const u16* __restrict__ A2,
    const float* __restrict__ bias0, const float* __restrict__ bias1, const float* __restrict__ bias2,
    const u16* __restrict__ BTb, void* __restrict__ Cb, void* __restrict__ Cb2,
    int M, int N, int K, size_t sBT, size_t sC, size_t sWhich)
{
    const int z = blockIdx.z;
    const int which = (NA == 3) ? (z % 3) : 0;
    const int b     = (NA == 3) ? (z / 3) : z;
    const u16* __restrict__ A = (which == 0) ? A0 : (which == 1) ? A1 : A2;
    const float* __restrict__ bias = (which == 0) ? bias0 : (which == 1) ? bias1 : bias2;
    const u16* __restrict__ BT = BTb + (size_t)b * sBT;

    // XCD-contiguous tile remap: XCD k (= lin%8) owns 2 N-columns x all 16 M-tiles
    const int lin  = blockIdx.x + (blockIdx.y << 4);
    const int lin2 = ((lin & 7) << 5) + (lin >> 3);
    const int n0 = (lin2 >> 4) * 64;
    const int m0 = (lin2 & 15) * 128;

    constexpr int BKv = (BUFS <= 3) ? 64 : 32;
    __shared__ u16 lA[BUFS * 128 * BKv];
    __shared__ u16 lB[BUFS * 64 * BKv];

    const int t = threadIdx.x, lane = t & 63, wave = t >> 6;
    const int wm = (wave >> 1) * 64, wn = (wave & 1) * 32;
    const int rl = lane & 15, kh = lane >> 4;

    fx4 acc[4][2];
    #pragma unroll
    for (int i = 0; i < 4; ++i)
        #pragma unroll
        for (int j = 0; j < 2; ++j) acc[i][j] = (fx4){0.f, 0.f, 0.f, 0.f};

    const int NT = K / BKv;

    if (BUFS <= 3) {
        // ===== BK=64 paths =====
        // staging: A 1024 16B-slots (4/thread), B 512 slots (2/thread).
        // slot s -> row s>>3, chunk-pos s&7; src chunk = pos ^ (row&7)
        const u16* gAp[4]; int dA[4];
        #pragma unroll
        for (int i = 0; i < 4; ++i) {
            int s = t + i * 256, row = s >> 3, src = (s & 7) ^ (row & 7);
            dA[i] = s * 8;
            gAp[i] = A + (size_t)(m0 + row) * K + src * 8;
        }
        const u16* gBp[2]; int dB[2];
        #pragma unroll
        for (int i = 0; i < 2; ++i) {
            int s = t + i * 256, row = s >> 3, src = (s & 7) ^ (row & 7);
            dB[i] = s * 8;
            gBp[i] = BT + (size_t)(n0 + row) * K + src * 8;
        }
        // frag offsets: half h, k-chunk c = h*4+kh; row r -> r*64 + ((c^(r&7))*8)
        int aoff[2][4], boff[2][2];
        #pragma unroll
        for (int h = 0; h < 2; ++h) {
            #pragma unroll
            for (int f = 0; f < 4; ++f) {
                int ra = wm + f * 16 + rl;
                aoff[h][f] = ra * 64 + (((h * 4 + kh) ^ (ra & 7)) * 8);
            }
            #pragma unroll
            for (int f = 0; f < 2; ++f) {
                int rb = wn + f * 16 + rl;
                boff[h][f] = rb * 64 + (((h * 4 + kh) ^ (rb & 7)) * 8);
            }
        }
#define STAGE64(BF, K0) do { \
        gld16(gAp[0] + (K0), &lA[(BF) * 128 * 64 + dA[0]]); \
        gld16(gAp[1] + (K0), &lA[(BF) * 128 * 64 + dA[1]]); \
        gld16(gAp[2] + (K0), &lA[(BF) * 128 * 64 + dA[2]]); \
        gld16(gAp[3] + (K0), &lA[(BF) * 128 * 64 + dA[3]]); \
        gld16(gBp[0] + (K0), &lB[(BF) * 64 * 64 + dB[0]]); \
        gld16(gBp[1] + (K0), &lB[(BF) * 64 * 64 + dB[1]]); } while (0)

#define COMPUTE64(BF) do { \
        const u16* bA_ = &lA[(BF) * 128 * 64]; \
        const u16* bB_ = &lB[(BF) * 64 * 64]; \
        __builtin_amdgcn_s_setprio(1); \
        _Pragma("unroll") \
        for (int h = 0; h < 2; ++h) { \
            bfx8 af[4], bfr[2]; \
            af[0] = *(const bfx8*)&bA_[aoff[h][0]]; \
            af[1] = *(const bfx8*)&bA_[aoff[h][1]]; \
            af[2] = *(const bfx8*)&bA_[aoff[h][2]]; \
            af[3] = *(const bfx8*)&bA_[aoff[h][3]]; \
            bfr[0] = *(const bfx8*)&bB_[boff[h][0]]; \
            bfr[1] = *(const bfx8*)&bB_[boff[h][1]]; \
            _Pragma("unroll") \
            for (int fm = 0; fm < 4; ++fm) \
                _Pragma("unroll") \
                for (int fn = 0; fn < 2; ++fn) \
                    acc[fm][fn] = MFMA16(af[fm], bfr[fn], acc[fm][fn], 0, 0, 0); \
        } \
        __builtin_amdgcn_s_setprio(0); } while (0)

        if (BUFS == 3) {
            STAGE64(0, 0); STAGE64(1, 64);
            int bcur = 0, bst = 2;
            for (int it = 0; it < NT; ++it) {
                if (it + 1 < NT) { WAIT_VM(6); } else { WAIT_VM(0); }
                SBAR(); SFENCE();
                if (it + 2 < NT) STAGE64(bst, (it + 2) << 6);
                COMPUTE64(bcur);
                if (++bcur == 3) bcur = 0;
                if (++bst == 3) bst = 0;
            }
        } else {
            // BUFS=2: depth-1, 48 KB -> 3 blocks/CU
            STAGE64(0, 0);
            for (int it = 0; it < NT; ++it) {
                WAIT_VM(0);            // only tile-it's 6 loads in flight
                SBAR(); SFENCE();
                if (it + 1 < NT) STAGE64((it + 1) & 1, (it + 1) << 6);
                COMPUTE64(it & 1);
            }
        }
#undef STAGE64
#undef COMPUTE64
    } else {
        // ===== BK=32 paths (legacy) =====
        const int sA0 = t, sA1 = t + 256, sB = t;
        const int rA0 = sA0 >> 2, cA0 = (sA0 & 3) ^ ((rA0 >> 1) & 3);
        const int rA1 = sA1 >> 2, cA1 = (sA1 & 3) ^ ((rA1 >> 1) & 3);
        const int rB  = sB  >> 2, cB  = (sB  & 3) ^ ((rB  >> 1) & 3);
        const u16* gA0 = A  + (size_t)(m0 + rA0) * K + cA0 * 8;
        const u16* gA1 = A  + (size_t)(m0 + rA1) * K + cA1 * 8;
        const u16* gB0 = BT + (size_t)(n0 + rB) * K + cB * 8;

        int aoff[4], boff[2];
        #pragma unroll
        for (int f = 0; f < 4; ++f) {
            int ra = wm + f * 16 + rl;
            aoff[f] = ra * 32 + ((kh ^ ((ra >> 1) & 3)) * 8);
        }
        #pragma unroll
        for (int f = 0; f < 2; ++f) {
            int rb = wn + f * 16 + rl;
            boff[f] = rb * 32 + ((kh ^ ((rb >> 1) & 3)) * 8);
        }

#define STAGE32(BF, K0) do { \
        gld16(gA0 + (K0), &lA[(BF) * 128 * 32 + sA0 * 8]); \
        gld16(gA1 + (K0), &lA[(BF) * 128 * 32 + sA1 * 8]); \
        gld16(gB0 + (K0), &lB[(BF) * 64 * 32 + sB * 8]); } while (0)

#define COMPUTE32(BF) do { \
        const u16* bA_ = &lA[(BF) * 128 * 32]; \
        const u16* bB_ = &lB[(BF) * 64 * 32]; \
        bfx8 af[4], bfr[2]; \
        af[0] = *(const bfx8*)&bA_[aoff[0]]; \
        af[1] = *(const bfx8*)&bA_[aoff[1]]; \
        af[2] = *(const bfx8*)&bA_[aoff[2]]; \
        af[3] = *(const bfx8*)&bA_[aoff[3]]; \
        bfr[0] = *(const bfx8*)&bB_[boff[0]]; \
        bfr[1] = *(const bfx8*)&bB_[boff[1]]; \
        __builtin_amdgcn_s_setprio(1); \
        _Pragma("unroll") \
        for (int fm = 0; fm < 4; ++fm) \
            _Pragma("unroll") \
            for (int fn = 0; fn < 2; ++fn) \
                acc[fm][fn] = MFMA16(af[fm], bfr[fn], acc[fm][fn], 0, 0, 0); \
        __builtin_amdgcn_s_setprio(0); } while (0)

        if (BUFS == 6) {
            STAGE32(0, 0); STAGE32(1, 32); STAGE32(2, 64);
            WAIT_VM(6); SBAR(); SFENCE();
            int bcur = 0, bpre = 3;
            for (int it = 0; it < NT; ++it) {
                if (it + 3 < NT) {
                    STAGE32(bpre, (it + 3) << 5);
                    WAIT_VM(9);
                } else if (it + 2 < NT) {
                    WAIT_VM(6);
                } else if (it + 1 < NT) {
                    WAIT_VM(3);
                } else {
                    WAIT_VM(0);
                }
                SBAR(); SFENCE();
                COMPUTE32(bcur);
                if (++bcur == 6) bcur = 0;
                if (++bpre == 6) bpre = 0;
            }
        } else {
            STAGE32(0, 0); STAGE32(1, 32); STAGE32(2, 64);
            for (int it = 0; it < NT; ++it) {
                const int rem = NT - 1 - it;
                if (rem >= 2) { WAIT_VM(6); }
                else if (rem == 1) { WAIT_VM(3); }
                else { WAIT_VM(0); }
                SBAR(); SFENCE();
                if (it + 3 < NT) STAGE32((it + 3) & 3, (it + 3) << 5);
                COMPUTE32(it & 3);
            }
        }
#undef STAGE32
#undef COMPUTE32
    }

    if (NA == 3 && which == 2) {
        // v: store normal orientation bf16 [b][M][N]
        u16* Vn = (u16*)Cb2 + (size_t)b * (size_t)M * N;
        #pragma unroll
        for (int fm = 0; fm < 4; ++fm) {
            int mg = m0 + wm + fm * 16 + kh * 4;
            #pragma unroll
            for (int fn = 0; fn < 2; ++fn) {
                int ng = n0 + wn + fn * 16 + rl;
                #pragma unroll
                for (int r = 0; r < 4; ++r)
                    Vn[(size_t)(mg + r) * N + ng] = f2b(acc[fm][fn][r] + bias[mg + r]);
            }
        }
    } else if (CT_OUT) {
        const float sc = (NA == 3 && which == 0) ? 0.125f : 1.0f;
        u16* CT = (u16*)Cb + (size_t)which * sWhich + (size_t)b * sC;
        #pragma unroll
        for (int fm = 0; fm < 4; ++fm) {
            int mg = m0 + wm + fm * 16 + kh * 4;
            float bi0 = bias[mg], bi1 = bias[mg + 1], bi2 = bias[mg + 2], bi3 = bias[mg + 3];
            #pragma unroll
            for (int fn = 0; fn < 2; ++fn) {
                int ng = n0 + wn + fn * 16 + rl;
                float v0 = (acc[fm][fn][0] + bi0) * sc;
                float v1 = (acc[fm][fn][1] + bi1) * sc;
                float v2 = (acc[fm][fn][2] + bi2) * sc;
                float v3 = (acc[fm][fn][3] + bi3) * sc;
                if (RELU) {
                    v0 = fmaxf(v0, 0.f); v1 = fmaxf(v1, 0.f);
                    v2 = fmaxf(v2, 0.f); v3 = fmaxf(v3, 0.f);
                }
                us4 o = { f2b(v0), f2b(v1), f2b(v2), f2b(v3) };
                *(us4*)(CT + (size_t)ng * M + mg) = o;
            }
        }
    } else {
        float* C = (float*)Cb + (size_t)b * sC;
        #pragma unroll
        for (int fm = 0; fm < 4; ++fm) {
            int mg = m0 + wm + fm * 16 + kh * 4;
            #pragma unroll
            for (int fn = 0; fn < 2; ++fn) {
                int ng = n0 + wn + fn * 16 + rl;
                #pragma unroll
                for (int r = 0; r < 4; ++r) {
                    float v = acc[fm][fn][r] + bias[mg + r];
                    if (RELU) v = fmaxf(v, 0.f);
                    C[(size_t)(mg + r) * N + ng] = v;
                }
            }
        }
    }
}

// ---------------------------------------------------------------------------
// Pass A (BANDED +-1 tile, W=64): S[l] = sum_{m in tiles [lt-1,lt+1]}
// exp(att[l,m] - |l-m|/8). Verified numerically free in R12/R13.
// Block = 64 l-rows of one (b,h). grid (16, B*H). Depth-2 prefetch.
// ---------------------------------------------------------------------------
__global__ __launch_bounds__(256) void attn_stats(
    const u16* __restrict__ qT, const u16* __restrict__ kT,
    float* __restrict__ rinv)
{
    const int lt = blockIdx.x;
    const int bh = blockIdx.y;
    const int b = bh >> 5, h = bh & 31;
    const size_t base = (size_t)b * L * AF + h * DH;

    const int mlo = lt < 1 ? 0 : lt - 1;
    const int mhi = lt > 14 ? 15 : lt + 1;
    const int NTW = mhi - mlo + 1;   // 2..3 always

    __shared__ u16 lq[64 * 64];
    __shared__ u16 lk[4][64 * 64];
    __shared__ float sS[4][64];

    const int t = threadIdx.x, lane = t & 63, wave = t >> 6;
    const int rl = lane & 15, g = lane >> 4;

    const int s0 = t, s1 = t + 256;
    const int r0 = s0 >> 3, cs0 = (s0 & 7) ^ (r0 & 7);
    const int r1 = s1 >> 3, cs1 = (s1 & 7) ^ (r1 & 7);

    const u16* gk0 = kT + base + (size_t)(mlo * 64 + r0) * AF + cs0 * 8;
    const u16* gk1 = kT + base + (size_t)(mlo * 64 + r1) * AF + cs1 * 8;

    gld16(qT + base + (size_t)(lt * 64 + r0) * AF + cs0 * 8, lq + s0 * 8);
    gld16(qT + base + (size_t)(lt * 64 + r1) * AF + cs1 * 8, lq + s1 * 8);
    gld16(gk0, &lk[0][s0 * 8]);
    gld16(gk1, &lk[0][s1 * 8]);
    gld16(gk0 + (size_t)64 * AF, &lk[1][s0 * 8]);
    gld16(gk1 + (size_t)64 * AF, &lk[1][s1 * 8]);
    WAIT_VM(2); SBAR(); SFENCE();    // q + k0 landed

    const int rmr = wave * 16 + rl;
    const int akoff0 = rmr * 64 + ((g ^ (rmr & 7)) * 8);
    const int akoff1 = rmr * 64 + (((g + 4) ^ (rmr & 7)) * 8);
    bfx8 qf0[4], qf1[4];
    #pragma unroll
    for (int f = 0; f < 4; ++f) {
        int rq = f * 16 + rl;
        qf0[f] = *(const bfx8*)&lq[rq * 64 + ((g ^ (rq & 7)) * 8)];
        qf1[f] = *(const bfx8*)&lq[rq * 64 + (((g + 4) ^ (rq & 7)) * 8)];
    }

    float Sx[4] = {0.f, 0.f, 0.f, 0.f};
    for (int i = 0; i < NTW; ++i) {
        if (i + 2 < NTW) {
            const int bf = (i + 2) & 3;
            gld16(gk0 + (size_t)(i + 2) * 64 * AF, &lk[bf][s0 * 8]);
            gld16(gk1 + (size_t)(i + 2) * 64 * AF, &lk[bf][s1 * 8]);
            WAIT_VM(4);
        } else if (i + 1 < NTW) {
            WAIT_VM(2);
        } else {
            WAIT_VM(0);
        }
        SBAR(); SFENCE();
        const u16* kb = lk[i & 3];
        bfx8 ak0 = *(const bfx8*)&kb[akoff0];
        bfx8 ak1 = *(const bfx8*)&kb[akoff1];
        const float mb = (float)((mlo + i) * 64 + wave * 16 + g * 4);
        #pragma unroll
        for (int fn = 0; fn < 4; ++fn) {
            fx4 att = (fx4){0.f, 0.f, 0.f, 0.f};
            att = MFMA16(ak0, qf0[fn], att, 0, 0, 0);
            att = MFMA16(ak1, qf1[fn], att, 0, 0, 0);
            const float lgf = (float)(lt * 64 + fn * 16 + rl);
            float e0 = __expf(att[0] - 0.125f * fabsf(lgf - mb));
            float e1 = __expf(att[1] - 0.125f * fabsf(lgf - (mb + 1.f)));
            float e2 = __expf(att[2] - 0.125f * fabsf(lgf - (mb + 2.f)));
            float e3 = __expf(att[3] - 0.125f * fabsf(lgf - (mb + 3.f)));
            Sx[fn] += (e0 + e1) + (e2 + e3);
        }
    }
    #pragma unroll
    for (int fn = 0; fn < 4; ++fn) {
        float s_ = Sx[fn];
        s_ += __shfl_xor(s_, 16);
        s_ += __shfl_xor(s_, 32);
        if (lane < 16) sS[wave][fn * 16 + rl] = s_;
    }
    __syncthreads();
    if (t < 64) {
        float s_ = sS[0][t] + sS[1][t] + sS[2][t] + sS[3][t];
        rinv[(size_t)bh * L + lt * 64 + t] = 1.0f / s_;
    }
}

// ---------------------------------------------------------------------------
// Pass B (BANDED +-1 tile): O[d,m] = sum over l-tiles [mt-1, mt] of
// v[d,l]*w[l,m]; h = relu(O) -> hT[b][m][h*64+d]. grid (16, B*H).
// ---------------------------------------------------------------------------
__global__ __launch_bounds__(256) void attn_pv(
    const u16* __restrict__ qT, const u16* __restrict__ kT, const u16* __restrict__ v,
    const float* __restrict__ rinv, u16* __restrict__ hT)
{
    const int mt = blockIdx.x;
    const int bh = blockIdx.y;
    const int b = bh >> 5, h = bh & 31;
    const size_t qkbase = (size_t)b * L * AF + h * DH;
    const size_t vbase  = ((size_t)b * AF + h * DH) * L;
    const size_t rbase  = (size_t)bh * L;

    const int ltlo = mt < 1 ? 0 : mt - 1;
    const int NI = mt - ltlo + 1;    // 1..2
    const int m0 = mt * 64;

    __shared__ u16 lkt[64 * 64];
    __shared__ u16 lqt[2][64 * 64], lv[2][64 * 64];
    __shared__ u16 lw[64 * 68];   // wT[m][l], pad 68

    const int t = threadIdx.x, lane = t & 63, wave = t >> 6;
    const int rl = lane & 15, g = lane >> 4;

    const int s0 = t, s1 = t + 256;
    const int r0 = s0 >> 3, cs0 = (s0 & 7) ^ (r0 & 7);
    const int r1 = s1 >> 3, cs1 = (s1 & 7) ^ (r1 & 7);

    const u16* gq0 = qT + qkbase + (size_t)(ltlo * 64 + r0) * AF + cs0 * 8;
    const u16* gq1 = qT + qkbase + (size_t)(ltlo * 64 + r1) * AF + cs1 * 8;
    const u16* gv0 = v + vbase + ltlo * 64 + (size_t)r0 * L + cs0 * 8;
    const u16* gv1 = v + vbase + ltlo * 64 + (size_t)r1 * L + cs1 * 8;

    const int rmr = wave * 16 + rl;     // phase-1 A rows (m), phase-2 A rows (d)
    const int toff0 = rmr * 64 + ((g ^ (rmr & 7)) * 8);
    const int toff1 = rmr * 64 + (((g + 4) ^ (rmr & 7)) * 8);
    int qoff0[4], qoff1[4];
    #pragma unroll
    for (int f = 0; f < 4; ++f) {
        int rq = f * 16 + rl;
        qoff0[f] = rq * 64 + ((g ^ (rq & 7)) * 8);
        qoff1[f] = rq * 64 + (((g + 4) ^ (rq & 7)) * 8);
    }

    // prologue: K-tile + first q/v tile
    gld16(kT + qkbase + (size_t)(m0 + r0) * AF + cs0 * 8, lkt + s0 * 8);
    gld16(kT + qkbase + (size_t)(m0 + r1) * AF + cs1 * 8, lkt + s1 * 8);
    gld16(gq0, &lqt[0][s0 * 8]);
    gld16(gq1, &lqt[0][s1 * 8]);
    gld16(gv0, &lv[0][s0 * 8]);
    gld16(gv1, &lv[0][s1 * 8]);
    WAIT_VM(0); SBAR(); SFENCE();

    fx4 oa[4];
    #pragma unroll
    for (int f = 0; f < 4; ++f) oa[f] = (fx4){0.f, 0.f, 0.f, 0.f};

    int cur = 0;
    for (int i = 0; i < NI; ++i) {
        const int lt = ltlo + i;
        if (i + 1 < NI) {   // prefetch next q/v tile into the other buffer
            gld16(gq0 + (size_t)(i + 1) * 64 * AF, &lqt[cur ^ 1][s0 * 8]);
            gld16(gq1 + (size_t)(i + 1) * 64 * AF, &lqt[cur ^ 1][s1 * 8]);
            gld16(gv0 + (i + 1) * 64, &lv[cur ^ 1][s0 * 8]);
            gld16(gv1 + (i + 1) * 64, &lv[cur ^ 1][s1 * 8]);
        }
        // phase 1: att^T[m][l] = mfma(kT rows m, qT rows l) -> weights in lw
        bfx8 ak0 = *(const bfx8*)&lkt[toff0];
        bfx8 ak1 = *(const bfx8*)&lkt[toff1];
        const u16* qb = lqt[cur];
        #pragma unroll
        for (int fn = 0; fn < 4; ++fn) {
            bfx8 q0 = *(const bfx8*)&qb[qoff0[fn]];
            bfx8 q1 = *(const bfx8*)&qb[qoff1[fn]];
            fx4 att = (fx4){0.f, 0.f, 0.f, 0.f};
            att = MFMA16(ak0, q0, att, 0, 0, 0);
            att = MFMA16(ak1, q1, att, 0, 0, 0);
            const int lg = lt * 64 + fn * 16 + rl;
            float ri = rinv[rbase + lg];
            const float db = (float)(lg - (m0 + wave * 16 + g * 4));
            #pragma unroll
            for (int r = 0; r < 4; ++r) {
                int mloc = wave * 16 + g * 4 + r;
                float s = att[r] - 0.125f * fabsf(db - (float)r);
                float w = (lg <= m0 + mloc) ? __expf(s) * ri : 0.f;
                lw[mloc * 68 + fn * 16 + rl] = f2b(w);
            }
        }
        WAIT_LGKM0(); SBAR(); SFENCE();   // lw visible; prefetch stays in flight

        // phase 2: O[d][m] += mfma(v rows d, wT rows m)
        const u16* vb = lv[cur];
        bfx8 av0 = *(const bfx8*)&vb[toff0];
        bfx8 av1 = *(const bfx8*)&vb[toff1];
        #pragma unroll
        for (int fn = 0; fn < 4; ++fn) {
            const u16* wrow = &lw[(fn * 16 + rl) * 68];
            union { bfx8 f; bfx4 hh[2]; } w0, w1;
            w0.hh[0] = *(const bfx4*)&wrow[g * 8];
            w0.hh[1] = *(const bfx4*)&wrow[g * 8 + 4];
            w1.hh[0] = *(const bfx4*)&wrow[(g + 4) * 8];
            w1.hh[1] = *(const bfx4*)&wrow[(g + 4) * 8 + 4];
            oa[fn] = MFMA16(av0, w0.f, oa[fn], 0, 0, 0);
            oa[fn] = MFMA16(av1, w1.f, oa[fn], 0, 0, 0);
        }
        WAIT_VM(0); WAIT_LGKM0(); SBAR(); SFENCE();   // next tile landed; reads done
        cur ^= 1;
    }

    // epilogue: relu, C^T store -> hT[b][m][h*64+d]
    #pragma unroll
    for (int fn = 0; fn < 4; ++fn) {
        int mg = m0 + fn * 16 + rl;
        int cg = h * DH + wave * 16 + g * 4;
        us4 o = { f2b(fmaxf(oa[fn][0], 0.f)), f2b(fmaxf(oa[fn][1], 0.f)),
                  f2b(fmaxf(oa[fn][2], 0.f)), f2b(fmaxf(oa[fn][3], 0.f)) };
        *(us4*)(hT + ((size_t)b * L + mg) * AF + cg) = o;
    }
}

// ---------------------------------------------------------------------------
extern "C" void kernel_launch(void* const* d_in, const int* in_sizes, int n_in,
                              void* d_out, int out_size, void* d_ws, size_t ws_size,
                              hipStream_t stream)
{
    (void)in_sizes; (void)n_in; (void)out_size; (void)ws_size;
    const float* x  = (const float*)d_in[0];
    const float* Wq = (const float*)d_in[1];
    const float* bq = (const float*)d_in[2];
    const float* Wk = (const float*)d_in[3];
    const float* bk = (const float*)d_in[4];
    const float* Wv = (const float*)d_in[5];
    const float* bv = (const float*)d_in[6];
    const float* W1 = (const float*)d_in[7];
    const float* b1 = (const float*)d_in[8];
    const float* W2 = (const float*)d_in[9];
    const float* b2 = (const float*)d_in[10];

    u16* wsp = (u16*)d_ws;
    size_t o = 0;
    u16* xT  = wsp + o; o += (size_t)NB * L * CIN;
    u16* qT  = wsp + o; o += (size_t)NB * L * AF;   // q (pre-scaled by 1/8), [b][l][af]
    u16* kT  = wsp + o; o += (size_t)NB * L * AF;   // must follow qT (which*sWhich)
    u16* vdm = wsp + o; o += (size_t)NB * AF * L;   // v normal orientation [b][af][l]
    u16* hT  = wsp + o; o += (size_t)NB * L * AF;
    u16* z1T = wsp + o; o += (size_t)NB * L * AF;
    u16* Wqb = wsp + o; o += (size_t)AF * CIN;
    u16* Wkb = wsp + o; o += (size_t)AF * CIN;
    u16* Wvb = wsp + o; o += (size_t)AF * CIN;
    u16* W1b = wsp + o; o += (size_t)AF * AF;
    u16* W2b = wsp + o; o += (size_t)AF * AF;
    float* rinv = (float*)(wsp + o); o += (size_t)NB * NH * L * 2;

    dim3 blk(256);

    prep<<<dim3(512, 1, 6), blk, 0, stream>>>(x, Wq, Wk, Wv, W1, W2,
                                              xT, Wqb, Wkb, Wvb, W1b, W2b);

    // QKV: qT/kT = (W? * x)^T (q scaled 1/8); v -> vdm normal orientation
    gemm_bt<0, 1, 3, 2><<<dim3(16, 16, NB * 3), blk, 0, stream>>>(
        Wqb, Wkb, Wvb, bq, bk, bv, xT, qT, vdm,
        AF, L, CIN, (size_t)L * CIN, (size_t)L * AF, (size_t)NB * L * AF);

    attn_stats<<<dim3(16, NB * NH), blk, 0, stream>>>(qT, kT, rinv);
    attn_pv<<<dim3(16, NB * NH), blk, 0, stream>>>(qT, kT, vdm, rinv, hT);

    // z1T = relu(W1*h + b1)^T  -- BUFS=2 (won R19)
    gemm_bt<1, 1, 1, 2><<<dim3(16, 16, NB), blk, 0, stream>>>(
        W1b, nullptr, nullptr, b1, nullptr, nullptr, hT, z1T, nullptr,
        AF, L, AF, (size_t)L * AF, (size_t)L * AF, 0);
    // out = W2*z1 + b2 (fp32) -- BUFS=2 TEST (last untested cell; R19=BUFS3
    // is the fallback if the fp32 epilogue loses at 3 blocks/CU again)
    gemm_bt<0, 0, 1, 2><<<dim3(16, 16, NB), blk, 0, stream>>>(
        W2b, nullptr, nullptr, b2, nullptr, nullptr, z1T, d_out, nullptr,
        AF, L, AF, (size_t)L * AF, (size_t)AF * L, 0);
}